// Round 11
// baseline (2207.530 us; speedup 1.0000x reference)
//
#include <hip/hip_runtime.h>
#include <hip/hip_bf16.h>
#include <math.h>

#define NB 128
#define NR 32
#define EPAD 40    // fA row stride in shorts
#define HPAD 136   // H/XA row stride in shorts (272B, 16B-aligned rows)
#define SCB 256    // scan blocks

// r26: 4-SUBTILE edge wave (64 edges/wave). r24 confirmed each halving of
// per-edge weight fetches pays (16->32 edges/wave: 228->176us). r25 node
// 2-subtile confirmed small (-48us total). r26 halves edge weight traffic
// again: 128 edges / 128 threads / 2 waves per block; per-kt weight
// fragments serve 4 M=16 subtiles. VGPR risk managed by split gather
// issue (subtiles 0-1 early, 2-3 post-GEMM2). LDS 45KB unchanged.
// Confirmed: r22 fast scan (-150), r24 edge 2-subtile (-284), r25 node
// 2-subtile (-48). Falsified: r5/r6/r7/r10/r12/r14/r16/r17/r18/r20/r21.

static constexpr float CUTOFF_F    = 10.0f;
static constexpr float RBF_STEP    = 10.0f / 31.0f;
static constexpr float RBF_COEFF   = -4.805f;           // -0.5/(10/31)^2
static constexpr float LOG2_F      = 0.69314718055994531f;
static constexpr float PI_OVER_CUT = 0.314159265358979f;

typedef __attribute__((ext_vector_type(8))) short bf16x8;
typedef __attribute__((ext_vector_type(2))) short bf16x2;
typedef __attribute__((ext_vector_type(4))) float f32x4;

__device__ __forceinline__ short f2bs(float x) {
    __hip_bfloat16 h = __float2bfloat16(x);   // RNE
    return *reinterpret_cast<short*>(&h);
}
__device__ __forceinline__ float bs2f(unsigned short u) {
    unsigned int v = ((unsigned int)u) << 16;
    return __uint_as_float(v);
}
__device__ __forceinline__ float ssp_f(float v) {
    return fmaxf(v, 0.0f) + __logf(1.0f + __expf(-fabsf(v))) - LOG2_F;
}
__device__ __forceinline__ float silu_f(float v) {
    return v / (1.0f + __expf(-v));
}

// packed bf16 atomic add (2 features per op)
__device__ __forceinline__ void atomic_pk_add_bf16(short* addr, float lo, float hi) {
#if __has_builtin(__builtin_amdgcn_global_atomic_fadd_v2bf16)
    typedef bf16x2 __attribute__((address_space(1))) *gptr;
    bf16x2 v;
    v[0] = f2bs(lo);
    v[1] = f2bs(hi);
    __builtin_amdgcn_global_atomic_fadd_v2bf16((gptr)(unsigned long long)addr, v);
#else
    unsigned int* w = (unsigned int*)addr;
    unsigned int old = *w, assumed;
    do {
        assumed = old;
        float fl = bs2f((unsigned short)(assumed & 0xffff)) + lo;
        float fh = bs2f((unsigned short)(assumed >> 16)) + hi;
        unsigned int nv = ((unsigned int)(unsigned short)f2bs(fh) << 16) |
                          (unsigned short)f2bs(fl);
        old = atomicCAS(w, assumed, nv);
    } while (old != assumed);
#endif
}

// flush one merged run: 8 accumulated features/lane -> 4 pk atomics/lane.
// Run boundaries are quad-uniform so the lane^1 shuffles pair active lanes.
__device__ __forceinline__ void flush_pk(short* aggrow, const float* accum, int col) {
    bool even = ((col & 1) == 0);
#pragma unroll
    for (int q = 0; q < 4; q++) {
        float a = accum[2 * q], b = accum[2 * q + 1];
        float pa = __shfl_xor(a, 1);   // feature (2q)*16 + (col^1)
        float pb = __shfl_xor(b, 1);
        int nbase = even ? (2 * q) * 16 + col : (2 * q + 1) * 16 + (col - 1);
        float lo = even ? a : pb;
        float hi = even ? pa : b;
        atomic_pk_add_bf16(aggrow + nbase, lo, hi);
    }
}

// ---------------------------------------------------------------------------
// Weight prep: dst[b][c][r] = bf16(src[b][r][c])
// ---------------------------------------------------------------------------
__global__ void transpose_cvt(const float* __restrict__ src, short* __restrict__ dst,
                              int R, int C, int total) {
    int t = blockIdx.x * blockDim.x + threadIdx.x;
    if (t >= total) return;
    int rc = R * C;
    int b = t / rc;
    int rem = t - b * rc;
    int c = rem / R;
    int r = rem - c * R;
    dst[t] = f2bs(src[(size_t)b * rc + (size_t)r * C + c]);
}

// ---------------------------------------------------------------------------
// Edge prep: distances + per-atom histogram. 4 edges/thread for MLP.
// ---------------------------------------------------------------------------
__global__ void edge_prep4(const float* __restrict__ pos,
                           const int* __restrict__ idx_i,
                           const int* __restrict__ idx_j,
                           float* __restrict__ d_ij,
                           int* __restrict__ hist,
                           int E) {
    int b0 = blockIdx.x * 1024 + threadIdx.x;
    int ia[4], ib[4];
    bool val[4];
#pragma unroll
    for (int k = 0; k < 4; k++) {
        int e = b0 + k * 256;
        val[k] = (e < E);
        ia[k] = val[k] ? idx_i[e] : 0;
        ib[k] = val[k] ? idx_j[e] : 0;
    }
    float ax[4], ay[4], az[4], bx[4], by[4], bz[4];
#pragma unroll
    for (int k = 0; k < 4; k++) {
        const float* pa = pos + ia[k] * 3;
        ax[k] = pa[0]; ay[k] = pa[1]; az[k] = pa[2];
    }
#pragma unroll
    for (int k = 0; k < 4; k++) {
        const float* pb = pos + ib[k] * 3;
        bx[k] = pb[0]; by[k] = pb[1]; bz[k] = pb[2];
    }
#pragma unroll
    for (int k = 0; k < 4; k++) {
        if (!val[k]) continue;
        float dx = ax[k] - bx[k], dy = ay[k] - by[k], dz = az[k] - bz[k];
        float d = sqrtf(dx * dx + dy * dy + dz * dz);
        d_ij[b0 + k * 256] = d;
        if (d < CUTOFF_F) atomicAdd(&hist[ia[k]], 1);
    }
}

// ---------------------------------------------------------------------------
// Multi-block exclusive scan of hist[N] -> cursor[N]  (r22, ~12us).
// ---------------------------------------------------------------------------
__global__ __launch_bounds__(256) void scan_reduce(const int* __restrict__ hist,
                                                   int* __restrict__ partial, int N) {
    __shared__ int red[256];
    int b = blockIdx.x;
    int chunk = (N + SCB - 1) / SCB;
    int lo = b * chunk;
    int hi = min(lo + chunk, N);
    int s = 0;
    for (int i = lo + threadIdx.x; i < hi; i += 256) s += hist[i];
    red[threadIdx.x] = s;
    __syncthreads();
    for (int d = 128; d > 0; d >>= 1) {
        if (threadIdx.x < d) red[threadIdx.x] += red[threadIdx.x + d];
        __syncthreads();
    }
    if (threadIdx.x == 0) partial[b] = red[0];
}

__global__ __launch_bounds__(256) void scan_partials(int* __restrict__ partial) {
    __shared__ int sm[SCB];
    int t = threadIdx.x;
    sm[t] = partial[t];
    __syncthreads();
    for (int d = 1; d < SCB; d <<= 1) {
        int v = (t >= d) ? sm[t - d] : 0;
        __syncthreads();
        sm[t] += v;
        __syncthreads();
    }
    partial[t] = (t == 0) ? 0 : sm[t - 1];   // exclusive
}

__global__ __launch_bounds__(256) void scan_expand(const int* __restrict__ hist,
                                                   const int* __restrict__ partial,
                                                   int* __restrict__ cursor, int N) {
    __shared__ int tsum[256];
    int b = blockIdx.x;
    int chunk = (N + SCB - 1) / SCB;
    int lo = b * chunk;
    int hi = min(lo + chunk, N);
    int sub = (chunk + 255) / 256;
    int tlo = lo + threadIdx.x * sub;
    int thi = min(tlo + sub, hi);
    int s = 0;
    for (int i = tlo; i < thi; i++) s += hist[i];
    int t = threadIdx.x;
    tsum[t] = s;
    __syncthreads();
    for (int d = 1; d < 256; d <<= 1) {
        int v = (t >= d) ? tsum[t - d] : 0;
        __syncthreads();
        tsum[t] += v;
        __syncthreads();
    }
    int run = partial[b] + ((t == 0) ? 0 : tsum[t - 1]);
    for (int i = tlo; i < thi; i++) {
        cursor[i] = run;
        run += hist[i];
    }
}

// ---------------------------------------------------------------------------
// Scatter active edges into idx_i-grouped order. 4 edges/thread for MLP.
// Computes rcut for active edges only. After: cursor[a] == end of range.
// ---------------------------------------------------------------------------
__global__ void scatter_sorted4(const float* __restrict__ d_ij,
                                const int* __restrict__ idx_i,
                                const int* __restrict__ idx_j,
                                const int* __restrict__ edge_attr,
                                int* __restrict__ cursor,
                                float4* __restrict__ edata,
                                int* __restrict__ sIarr, int E) {
    int b0 = blockIdx.x * 1024 + threadIdx.x;
    float d[4]; int ii[4], jj[4], at[4]; bool act[4];
#pragma unroll
    for (int k = 0; k < 4; k++) {
        int e = b0 + k * 256;
        bool v = (e < E);
        d[k] = v ? d_ij[e] : 1e9f;
        act[k] = (d[k] < CUTOFF_F);
        ii[k] = act[k] ? idx_i[e] : 0;
        jj[k] = act[k] ? idx_j[e] : 0;
        at[k] = act[k] ? edge_attr[e] : 0;
    }
    int p[4];
#pragma unroll
    for (int k = 0; k < 4; k++)
        if (act[k]) p[k] = atomicAdd(&cursor[ii[k]], 1);
#pragma unroll
    for (int k = 0; k < 4; k++) {
        if (!act[k]) continue;
        float4 v;
        v.x = d[k];
        v.y = 0.5f * (__cosf(d[k] * PI_OVER_CUT) + 1.0f);
        v.z = __int_as_float(jj[k]);
        v.w = __int_as_float(at[k]);
        edata[p[k]] = v;
        sIarr[p[k]] = ii[k];
    }
}

// ---------------------------------------------------------------------------
// x = ele_emb[z] + res_emb[z_res]
// ---------------------------------------------------------------------------
__global__ void atom_embed(const int* __restrict__ z,
                           const int* __restrict__ z_res,
                           const float* __restrict__ ele_emb,
                           const float* __restrict__ res_emb,
                           float* __restrict__ x, int N) {
    int t = blockIdx.x * blockDim.x + threadIdx.x;
    if (t >= N * NB) return;
    int n = t >> 7, c = t & 127;
    x[t] = ele_emb[z[n] * NB + c] + res_emb[z_res[n] * NB + c];
}

// ---------------------------------------------------------------------------
// xf(bf16, permuted cols) = in(fp32) @ W  via MFMA. First-iteration in2f.
// ---------------------------------------------------------------------------
__global__ __launch_bounds__(256, 4) void node_in2f_mfma(
    const float* __restrict__ x, const short* __restrict__ WT,
    short* __restrict__ xf, int N) {
    __shared__ __align__(16) short XA[64 * HPAD];
    int a0 = blockIdx.x * 64;
    int t = threadIdx.x;
#pragma unroll
    for (int c = 0; c < 4; c++) {
        int chunk = t + c * 256;
        int row = chunk >> 4;
        int col = (chunk & 15) * 8;
        short v[8];
        if (a0 + row < N) {
            const float* src = x + (size_t)(a0 + row) * NB + col;
            float4 f0 = *(const float4*)src;
            float4 f1 = *(const float4*)(src + 4);
            v[0] = f2bs(f0.x); v[1] = f2bs(f0.y); v[2] = f2bs(f0.z); v[3] = f2bs(f0.w);
            v[4] = f2bs(f1.x); v[5] = f2bs(f1.y); v[6] = f2bs(f1.z); v[7] = f2bs(f1.w);
        } else {
#pragma unroll
            for (int j = 0; j < 8; j++) v[j] = 0;
        }
        *(bf16x8*)&XA[row * HPAD + col] = *(bf16x8*)v;
    }
    __syncthreads();

    int wid = t >> 6, lane = t & 63;
    int quad = lane >> 4, col = lane & 15;
    int mrow = wid * 16 + col;

    f32x4 acc[8] = {};
#pragma unroll
    for (int kt = 0; kt < 4; kt++) {
        bf16x8 a = *(bf16x8*)&XA[mrow * HPAD + kt * 32 + quad * 8];
#pragma unroll
        for (int nt = 0; nt < 8; nt++) {
            bf16x8 b = *(const bf16x8*)&WT[(nt * 16 + col) * NB + kt * 32 + quad * 8];
            acc[nt] = __builtin_amdgcn_mfma_f32_16x16x32_bf16(a, b, acc[nt], 0, 0, 0);
        }
    }
#pragma unroll
    for (int nt = 0; nt < 8; nt++) {
        int cst = col * 8 + nt;   // permuted storage col
#pragma unroll
        for (int r = 0; r < 4; r++) {
            int m = wid * 16 + quad * 4 + r;
            if (a0 + m < N) xf[(size_t)(a0 + m) * NB + cst] = f2bs(acc[nt][r]);
        }
    }
}

// ---------------------------------------------------------------------------
// 2-SUBTILE node_fused (r25, confirmed): v = ssp(agg@W1+b1)@W2+b2 ; x += v ;
// xf_next(bf16, permuted) = x @ Wn. 128 threads / 2 waves per 64-atom
// block; per-kt weight fragments loaded once per wave, consumed by both
// subtiles. Staging wave-local -> barrier-free. Re-zeroes its agg rows.
// ---------------------------------------------------------------------------
__global__ __launch_bounds__(128, 1) void node_fused_mfma(
    short* __restrict__ agg,
    const short* __restrict__ W1T, const float* __restrict__ b1,
    const short* __restrict__ W2T, const float* __restrict__ b2,
    const short* __restrict__ WnT,
    float* __restrict__ x, short* __restrict__ xf, int N) {
    __shared__ __align__(16) short XA[64 * HPAD];
    __shared__ __align__(16) short H[64 * HPAD];
    int a0 = blockIdx.x * 64;
    int t = threadIdx.x;                 // [0,128)
    int wid = t >> 6, lane = t & 63;     // 2 waves
    int quad = lane >> 4, col = lane & 15;

    // wave-local staging: wave wid stages its own rows [wid*32, wid*32+32)
#pragma unroll
    for (int c = 0; c < 8; c++) {
        int chunk = lane + c * 64;            // [0,512)
        int row = wid * 32 + (chunk >> 4);    // wave-local row
        int colb = (chunk & 15) * 8;
        bf16x8 v = {0, 0, 0, 0, 0, 0, 0, 0};
        if (a0 + row < N) {
            short* src = agg + (size_t)(a0 + row) * NB + colb;
            v = *(const bf16x8*)src;
            *(bf16x8*)src = (bf16x8){0, 0, 0, 0, 0, 0, 0, 0};  // re-zero
        }
        *(bf16x8*)&XA[row * HPAD + colb] = v;
    }
    asm volatile("s_waitcnt lgkmcnt(0)" ::: "memory");
    __builtin_amdgcn_sched_barrier(0);

    // GEMM1 + ssp -> H (2 subtiles, weights loaded once per kt)
    {
        f32x4 acc[2][8] = {};
#pragma unroll
        for (int kt = 0; kt < 4; kt++) {
            bf16x8 bf[8];
#pragma unroll
            for (int nt = 0; nt < 8; nt++)
                bf[nt] = *(const bf16x8*)&W1T[(nt * 16 + col) * NB + kt * 32 + quad * 8];
#pragma unroll
            for (int s = 0; s < 2; s++) {
                bf16x8 a = *(bf16x8*)&XA[(wid * 32 + s * 16 + col) * HPAD + kt * 32 + quad * 8];
#pragma unroll
                for (int nt = 0; nt < 8; nt++)
                    acc[s][nt] = __builtin_amdgcn_mfma_f32_16x16x32_bf16(a, bf[nt], acc[s][nt], 0, 0, 0);
            }
        }
#pragma unroll
        for (int s = 0; s < 2; s++) {
#pragma unroll
            for (int nt = 0; nt < 8; nt++) {
                int n = nt * 16 + col;
                float bias = b1[n];
#pragma unroll
                for (int r = 0; r < 4; r++) {
                    int m = wid * 32 + s * 16 + quad * 4 + r;
                    H[m * HPAD + n] = f2bs(ssp_f(acc[s][nt][r] + bias));
                }
            }
        }
    }
    asm volatile("s_waitcnt lgkmcnt(0)" ::: "memory");
    __builtin_amdgcn_sched_barrier(0);

    // GEMM2 + residual: x_new -> global fp32 + XA bf16 (reuse)
    {
        f32x4 acc[2][8] = {};
#pragma unroll
        for (int kt = 0; kt < 4; kt++) {
            bf16x8 bf[8];
#pragma unroll
            for (int nt = 0; nt < 8; nt++)
                bf[nt] = *(const bf16x8*)&W2T[(nt * 16 + col) * NB + kt * 32 + quad * 8];
#pragma unroll
            for (int s = 0; s < 2; s++) {
                bf16x8 a = *(bf16x8*)&H[(wid * 32 + s * 16 + col) * HPAD + kt * 32 + quad * 8];
#pragma unroll
                for (int nt = 0; nt < 8; nt++)
                    acc[s][nt] = __builtin_amdgcn_mfma_f32_16x16x32_bf16(a, bf[nt], acc[s][nt], 0, 0, 0);
            }
        }
#pragma unroll
        for (int s = 0; s < 2; s++) {
#pragma unroll
            for (int nt = 0; nt < 8; nt++) {
                int n = nt * 16 + col;
                float bias = b2[n];
#pragma unroll
                for (int r = 0; r < 4; r++) {
                    int m = wid * 32 + s * 16 + quad * 4 + r;
                    float xn = 0.0f;
                    if (a0 + m < N) {
                        size_t o = (size_t)(a0 + m) * NB + n;
                        xn = x[o] + acc[s][nt][r] + bias;
                        x[o] = xn;
                    }
                    XA[m * HPAD + n] = f2bs(xn);
                }
            }
        }
    }
    asm volatile("s_waitcnt lgkmcnt(0)" ::: "memory");
    __builtin_amdgcn_sched_barrier(0);

    // GEMM3: xf = x_new @ Wn  (bf16 out, permuted storage cols)
    {
        f32x4 acc[2][8] = {};
#pragma unroll
        for (int kt = 0; kt < 4; kt++) {
            bf16x8 bf[8];
#pragma unroll
            for (int nt = 0; nt < 8; nt++)
                bf[nt] = *(const bf16x8*)&WnT[(nt * 16 + col) * NB + kt * 32 + quad * 8];
#pragma unroll
            for (int s = 0; s < 2; s++) {
                bf16x8 a = *(bf16x8*)&XA[(wid * 32 + s * 16 + col) * HPAD + kt * 32 + quad * 8];
#pragma unroll
                for (int nt = 0; nt < 8; nt++)
                    acc[s][nt] = __builtin_amdgcn_mfma_f32_16x16x32_bf16(a, bf[nt], acc[s][nt], 0, 0, 0);
            }
        }
#pragma unroll
        for (int s = 0; s < 2; s++) {
#pragma unroll
            for (int nt = 0; nt < 8; nt++) {
                int cst = col * 8 + nt;
#pragma unroll
                for (int r = 0; r < 4; r++) {
                    int m = wid * 32 + s * 16 + quad * 4 + r;
                    if (a0 + m < N) xf[(size_t)(a0 + m) * NB + cst] = f2bs(acc[s][nt][r]);
                }
            }
        }
    }
}

// ---------------------------------------------------------------------------
// Last iteration fused with head: v = ssp(agg@W1+b1)@W2+b2 ; xn = x + v ;
// h = silu(xn/||xn||) ; silu(h@hW1+hb1)@hW2 ; segment-sum by batch.
// ---------------------------------------------------------------------------
__global__ __launch_bounds__(256, 4) void node_out_head_mfma(
    const short* __restrict__ agg,
    const short* __restrict__ W1T, const float* __restrict__ b1,
    const short* __restrict__ W2T, const float* __restrict__ b2,
    const float* __restrict__ x, const int* __restrict__ batch,
    const short* __restrict__ hW1T, const float* __restrict__ hb1,
    const float* __restrict__ hW2,
    float* __restrict__ out, int N) {
    __shared__ __align__(16) short XA[64 * HPAD];
    __shared__ __align__(16) short H[64 * HPAD];
    __shared__ int sbat[64];
    __shared__ float rowval[64];
    int a0 = blockIdx.x * 64;
    int t = threadIdx.x;

    if (t < 64) sbat[t] = (a0 + t < N) ? batch[a0 + t] : -1;
#pragma unroll
    for (int c = 0; c < 4; c++) {
        int chunk = t + c * 256;
        int row = chunk >> 4;
        int col = (chunk & 15) * 8;
        bf16x8 v = {0, 0, 0, 0, 0, 0, 0, 0};
        if (a0 + row < N) v = *(const bf16x8*)&agg[(size_t)(a0 + row) * NB + col];
        *(bf16x8*)&XA[row * HPAD + col] = v;
    }
    __syncthreads();

    int wid = t >> 6, lane = t & 63;
    int quad = lane >> 4, col = lane & 15;
    int mrow = wid * 16 + col;

    // GEMM1 + ssp -> H
    {
        f32x4 acc[8] = {};
#pragma unroll
        for (int kt = 0; kt < 4; kt++) {
            bf16x8 a = *(bf16x8*)&XA[mrow * HPAD + kt * 32 + quad * 8];
#pragma unroll
            for (int nt = 0; nt < 8; nt++) {
                bf16x8 b = *(const bf16x8*)&W1T[(nt * 16 + col) * NB + kt * 32 + quad * 8];
                acc[nt] = __builtin_amdgcn_mfma_f32_16x16x32_bf16(a, b, acc[nt], 0, 0, 0);
            }
        }
#pragma unroll
        for (int nt = 0; nt < 8; nt++) {
            int n = nt * 16 + col;
            float bias = b1[n];
#pragma unroll
            for (int r = 0; r < 4; r++) {
                int m = wid * 16 + quad * 4 + r;
                H[m * HPAD + n] = f2bs(ssp_f(acc[nt][r] + bias));
            }
        }
    }
    __syncthreads();

    // GEMM2 + residual in registers; row sums of squares via 16-lane shuffle
    float xnv[8][4];
    float ssq[4] = {0.f, 0.f, 0.f, 0.f};
    {
        f32x4 acc[8] = {};
#pragma unroll
        for (int kt = 0; kt < 4; kt++) {
            bf16x8 a = *(bf16x8*)&H[mrow * HPAD + kt * 32 + quad * 8];
#pragma unroll
            for (int nt = 0; nt < 8; nt++) {
                bf16x8 b = *(const bf16x8*)&W2T[(nt * 16 + col) * NB + kt * 32 + quad * 8];
                acc[nt] = __builtin_amdgcn_mfma_f32_16x16x32_bf16(a, b, acc[nt], 0, 0, 0);
            }
        }
#pragma unroll
        for (int nt = 0; nt < 8; nt++) {
            int n = nt * 16 + col;
            float bias = b2[n];
#pragma unroll
            for (int r = 0; r < 4; r++) {
                int m = wid * 16 + quad * 4 + r;
                float xn = 0.0f;
                if (a0 + m < N) xn = x[(size_t)(a0 + m) * NB + n] + acc[nt][r] + bias;
                xnv[nt][r] = xn;
                ssq[r] += xn * xn;
            }
        }
    }
#pragma unroll
    for (int r = 0; r < 4; r++) {
#pragma unroll
        for (int m = 1; m < 16; m <<= 1) ssq[r] += __shfl_xor(ssq[r], m);
    }
    float inv[4];
#pragma unroll
    for (int r = 0; r < 4; r++) inv[r] = 1.0f / fmaxf(sqrtf(ssq[r]), 1e-12f);
    __syncthreads();
#pragma unroll
    for (int nt = 0; nt < 8; nt++) {
        int n = nt * 16 + col;
#pragma unroll
        for (int r = 0; r < 4; r++) {
            int m = wid * 16 + quad * 4 + r;
            XA[m * HPAD + n] = f2bs(silu_f(xnv[nt][r] * inv[r]));
        }
    }
    __syncthreads();

    // head GEMM: silu(h@hW1+hb1) dot hW2 per row
    f32x4 acc[8] = {};
#pragma unroll
    for (int kt = 0; kt < 4; kt++) {
        bf16x8 a = *(bf16x8*)&XA[mrow * HPAD + kt * 32 + quad * 8];
#pragma unroll
        for (int nt = 0; nt < 8; nt++) {
            bf16x8 b = *(const bf16x8*)&hW1T[(nt * 16 + col) * NB + kt * 32 + quad * 8];
            acc[nt] = __builtin_amdgcn_mfma_f32_16x16x32_bf16(a, b, acc[nt], 0, 0, 0);
        }
    }
    float partial[4] = {0.f, 0.f, 0.f, 0.f};
#pragma unroll
    for (int nt = 0; nt < 8; nt++) {
        int n = nt * 16 + col;
        float bias = hb1[n];
        float w2 = hW2[n];
#pragma unroll
        for (int r = 0; r < 4; r++) partial[r] += silu_f(acc[nt][r] + bias) * w2;
    }
#pragma unroll
    for (int r = 0; r < 4; r++) {
#pragma unroll
        for (int d = 1; d < 16; d <<= 1) partial[r] += __shfl_xor(partial[r], d);
    }
    if (col == 0) {
#pragma unroll
        for (int r = 0; r < 4; r++) rowval[wid * 16 + quad * 4 + r] = partial[r];
    }
    __syncthreads();

    if (t < 64) {
        int b = sbat[t];
        bool headf = (b >= 0) && (t == 0 || sbat[t - 1] != b);
        if (headf) {
            float s = 0.0f;
            int rr = t;
            while (rr < 64 && sbat[rr] == b) { s += rowval[rr]; rr++; }
            atomicAdd(&out[b], s);
        }
    }
}

// ---------------------------------------------------------------------------
// BARRIER-FREE 4-subtile edge kernel (r26). 128 edges/block, 2 waves, each
// wave owns 64 contiguous edges as four M=16 subtiles. Weight B-fragments
// loaded once per kt per wave, reused by 4 subtiles (per-edge weight
// traffic halves again vs r24). Gathers split: s=0,1 early; s=2,3 after
// GEMM2 (caps VGPR pressure). fA/H wave-local; lgkmcnt fences.
// ---------------------------------------------------------------------------
__global__ __launch_bounds__(128) void edge_fused_mfma(
    const float4* __restrict__ edata, const int* __restrict__ sIarr,
    const int* __restrict__ rowend, int natoms,
    const float* __restrict__ edge_emb,
    const short* __restrict__ W1T, const float* __restrict__ b1,
    const short* __restrict__ W2T, const float* __restrict__ b2,
    const short* __restrict__ xf, short* __restrict__ agg) {
    __shared__ __align__(16) short fA[128 * EPAD];
    __shared__ __align__(16) short H[128 * HPAD];

    int t = threadIdx.x;                 // [0,128)
    int wid = t >> 6, lane = t & 63;     // 2 waves
    int quad = lane >> 4, col = lane & 15;
    int base = blockIdx.x * 128;
    int wbase = base + wid * 64;         // this wave's 64-edge window

    // lane holds the record of edge wbase+lane
    float4 ed = edata[wbase + lane];
    int sIv0 = sIarr[wbase + lane];
    int cnt = rowend[natoms - 1];
    if (base >= cnt) return;

    bool act = (wbase + lane) < cnt;
    float dv  = act ? ed.x : 1e9f;
    float rcv = act ? ed.y : 0.0f;
    int   jjv = act ? __float_as_int(ed.z) : 0;
    int   atv = act ? __float_as_int(ed.w) : 0;
    int   iiv = act ? sIv0 : 0;

    const unsigned short* xg = (const unsigned short*)xf;

    // stage A: f_ij tile (RBF + edge_emb), bf16. 64 rows x 4 chunks of 8.
    {
#pragma unroll
        for (int c = 0; c < 4; c++) {
            int chunk = lane + c * 64;       // [0,256)
            int row = chunk >> 2;            // [0,64)
            int r0 = (chunk & 3) * 8;
            float d  = __shfl(dv, row);
            int   at = __shfl(atv, row);
            const float* em = edge_emb + at * NR + r0;
            short v[8];
#pragma unroll
            for (int j = 0; j < 8; j++) {
                float off = (float)(r0 + j) * RBF_STEP;
                float dd = d - off;
                v[j] = f2bs(__expf(RBF_COEFF * dd * dd) + em[j]);
            }
            *(bf16x8*)&fA[(wid * 64 + row) * EPAD + r0] = *(bf16x8*)v;
        }
    }

    // early gathers for subtiles 0,1 (hide under GEMM1 + GEMM2)
    bf16x8 xv01[2][4];
#pragma unroll
    for (int s = 0; s < 2; s++) {
#pragma unroll
        for (int r = 0; r < 4; r++) {
            int jj = __shfl(jjv, s * 16 + quad * 4 + r);
            xv01[s][r] = *(const bf16x8*)&xg[(size_t)jj * NB + col * 8];
        }
    }

    // wave-local LDS fence: fA writes -> GEMM1 reads
    asm volatile("s_waitcnt lgkmcnt(0)" ::: "memory");
    __builtin_amdgcn_sched_barrier(0);

    // GEMM1: hidden = f_ij @ W1 (K=32), weights loaded ONCE for 4 subtiles
    {
        bf16x8 b1f[8];
#pragma unroll
        for (int nt = 0; nt < 8; nt++)
            b1f[nt] = *(const bf16x8*)&W1T[(nt * 16 + col) * NR + quad * 8];
#pragma unroll
        for (int s = 0; s < 4; s++) {
            bf16x8 a1 = *(bf16x8*)&fA[(wid * 64 + s * 16 + col) * EPAD + quad * 8];
            f32x4 acc[8];
#pragma unroll
            for (int nt = 0; nt < 8; nt++)
                acc[nt] = __builtin_amdgcn_mfma_f32_16x16x32_bf16(a1, b1f[nt], (f32x4){0.f, 0.f, 0.f, 0.f}, 0, 0, 0);
#pragma unroll
            for (int nt = 0; nt < 8; nt++) {
                int n = nt * 16 + col;
                float bias = b1[n];
#pragma unroll
                for (int r = 0; r < 4; r++) {
                    int m = wid * 64 + s * 16 + quad * 4 + r;
                    H[m * HPAD + n] = f2bs(ssp_f(acc[nt][r] + bias));
                }
            }
        }
    }

    // wave-local LDS fence: H writes -> GEMM2 reads
    asm volatile("s_waitcnt lgkmcnt(0)" ::: "memory");
    __builtin_amdgcn_sched_barrier(0);

    // GEMM2: Wij = hidden @ W2 (K=128); per-kt B-fragments loaded ONCE,
    // consumed by all 4 subtiles (quarter the per-edge weight traffic).
    f32x4 acc2[4][8] = {};
#pragma unroll
    for (int kt = 0; kt < 4; kt++) {
        bf16x8 b2f[8];
#pragma unroll
        for (int nt = 0; nt < 8; nt++)
            b2f[nt] = *(const bf16x8*)&W2T[(nt * 16 + col) * NB + kt * 32 + quad * 8];
#pragma unroll
        for (int s = 0; s < 4; s++) {
            bf16x8 a = *(bf16x8*)&H[(wid * 64 + s * 16 + col) * HPAD + kt * 32 + quad * 8];
#pragma unroll
            for (int nt = 0; nt < 8; nt++)
                acc2[s][nt] = __builtin_amdgcn_mfma_f32_16x16x32_bf16(a, b2f[nt], acc2[s][nt], 0, 0, 0);
        }
    }

    // late gathers for subtiles 2,3 (latency hides under epilogue 0,1)
    bf16x8 xv23[2][4];
#pragma unroll
    for (int s = 0; s < 2; s++) {
#pragma unroll
        for (int r = 0; r < 4; r++) {
            int jj = __shfl(jjv, (s + 2) * 16 + quad * 4 + r);
            xv23[s][r] = *(const bf16x8*)&xg[(size_t)jj * NB + col * 8];
        }
    }

    // epilogue: per subtile, merge equal-atom runs over the quad's 4 edges,
    // flush merged runs with pk atomics (quad-uniform branches).
    float b2v[8];
#pragma unroll
    for (int nt = 0; nt < 8; nt++) b2v[nt] = b2[nt * 16 + col];

#pragma unroll
    for (int s = 0; s < 4; s++) {
        int e0l = s * 16 + quad * 4;
        int cur = __shfl(iiv, e0l);
        float accum[8] = {0.f, 0.f, 0.f, 0.f, 0.f, 0.f, 0.f, 0.f};
#pragma unroll
        for (int r = 0; r < 4; r++) {
            int ii = __shfl(iiv, e0l + r);
            float rc = __shfl(rcv, e0l + r);
            if (ii != cur) {
                flush_pk(agg + (size_t)cur * NB, accum, col);
#pragma unroll
                for (int nt = 0; nt < 8; nt++) accum[nt] = 0.f;
                cur = ii;
            }
            bf16x8 xvv = (s < 2) ? xv01[s][r] : xv23[s - 2][r];
#pragma unroll
            for (int nt = 0; nt < 8; nt++) {
                float w = (acc2[s][nt][r] + b2v[nt]) * rc;
                accum[nt] = fmaf(w, bs2f((unsigned short)xvv[nt]), accum[nt]);
            }
        }
        flush_pk(agg + (size_t)cur * NB, accum, col);
    }
}

// ---------------------------------------------------------------------------
extern "C" void kernel_launch(void* const* d_in, const int* in_sizes, int n_in,
                              void* d_out, int out_size, void* d_ws, size_t ws_size,
                              hipStream_t stream) {
    const int*   z        = (const int*)d_in[0];
    const int*   z_res    = (const int*)d_in[1];
    const float* pos      = (const float*)d_in[2];
    const int*   idx_i    = (const int*)d_in[3];
    const int*   idx_j    = (const int*)d_in[4];
    const int*   edge_attr= (const int*)d_in[5];
    const int*   batch    = (const int*)d_in[6];
    const float* ele_emb  = (const float*)d_in[7];
    const float* res_emb  = (const float*)d_in[8];
    const float* edge_emb = (const float*)d_in[9];
    const float* in2f_W   = (const float*)d_in[10];
    const float* filt_W1  = (const float*)d_in[11];
    const float* filt_b1  = (const float*)d_in[12];
    const float* filt_W2  = (const float*)d_in[13];
    const float* filt_b2  = (const float*)d_in[14];
    const float* f2out_W1 = (const float*)d_in[15];
    const float* f2out_b1 = (const float*)d_in[16];
    const float* f2out_W2 = (const float*)d_in[17];
    const float* f2out_b2 = (const float*)d_in[18];
    const float* head_W1  = (const float*)d_in[19];
    const float* head_b1  = (const float*)d_in[20];
    const float* head_W2  = (const float*)d_in[21];

    const int N = in_sizes[0];
    const int E = in_sizes[3];

    char* p = (char*)d_ws;
    size_t off = 0;
    auto carve = [&](size_t bytes) -> void* {
        void* q = p + off;
        off = (off + bytes + 255) & ~(size_t)255;
        return q;
    };
    float*  d_d      = (float*)carve((size_t)E * 4);
    float4* edata    = (float4*)carve((size_t)E * 16);
    int*    sIarr    = (int*)carve((size_t)E * 4);
    int*    hist     = (int*)carve((size_t)N * 4);
    int*    cursor   = (int*)carve((size_t)N * 4);
    int*    partial  = (int*)carve((size_t)SCB * 4);
    float*  x_buf    = (float*)carve((size_t)N * NB * 4);
    short*  xf_buf   = (short*)carve((size_t)N * NB * 2);
    short*  agg      = (short*)carve((size_t)N * NB * 2);
    short*  in2f_WT  = (short*)carve((size_t)6 * NB * NB * 2);
    short*  fW1T     = (short*)carve((size_t)6 * NR * NB * 2);
    short*  fW2T     = (short*)carve((size_t)6 * NB * NB * 2);
    short*  oW1T     = (short*)carve((size_t)6 * NB * NB * 2);
    short*  oW2T     = (short*)carve((size_t)6 * NB * NB * 2);
    short*  hW1T     = (short*)carve((size_t)NB * NB * 2);
    (void)ws_size;

    // weight prep (bf16 transposed)
    {
        int tot = 6 * NB * NB;
        transpose_cvt<<<(tot + 255) / 256, 256, 0, stream>>>(in2f_W, in2f_WT, NB, NB, tot);
        transpose_cvt<<<(tot + 255) / 256, 256, 0, stream>>>(filt_W2, fW2T, NB, NB, tot);
        transpose_cvt<<<(tot + 255) / 256, 256, 0, stream>>>(f2out_W1, oW1T, NB, NB, tot);
        transpose_cvt<<<(tot + 255) / 256, 256, 0, stream>>>(f2out_W2, oW2T, NB, NB, tot);
        int tot1 = 6 * NR * NB;
        transpose_cvt<<<(tot1 + 255) / 256, 256, 0, stream>>>(filt_W1, fW1T, NR, NB, tot1);
        int tot2 = NB * NB;
        transpose_cvt<<<(tot2 + 255) / 256, 256, 0, stream>>>(head_W1, hW1T, NB, NB, tot2);
    }

    // edge prep + idx_i-grouped sort with packed records
    hipMemsetAsync(hist, 0, (size_t)N * 4, stream);
    int nblk_e4 = (E + 1023) / 1024;
    edge_prep4<<<nblk_e4, 256, 0, stream>>>(pos, idx_i, idx_j, d_d, hist, E);
    // multi-block exclusive scan: hist -> cursor (r22)
    scan_reduce<<<SCB, 256, 0, stream>>>(hist, partial, N);
    scan_partials<<<1, SCB, 0, stream>>>(partial);
    scan_expand<<<SCB, 256, 0, stream>>>(hist, partial, cursor, N);
    scatter_sorted4<<<nblk_e4, 256, 0, stream>>>(d_d, idx_i, idx_j, edge_attr,
                                                 cursor, edata, sIarr, E);
    // cursor[a] is now the END of atom a's sorted range; cursor[N-1] = count.

    atom_embed<<<(N * NB + 255) / 256, 256, 0, stream>>>(z, z_res, ele_emb, res_emb, x_buf, N);

    int nblk_atom64 = (N + 63) / 64;
    int nblk_edge = (E + 127) / 128;

    node_in2f_mfma<<<nblk_atom64, 256, 0, stream>>>(x_buf, in2f_WT, xf_buf, N);
    hipMemsetAsync(d_out, 0, (size_t)out_size * sizeof(float), stream);
    hipMemsetAsync(agg, 0, (size_t)N * NB * 2, stream);   // once; node_fused re-zeroes
    for (int i = 0; i < 6; i++) {
        edge_fused_mfma<<<nblk_edge, 128, 0, stream>>>(
            edata, sIarr, cursor, N, edge_emb,
            fW1T + (size_t)i * NR * NB, filt_b1 + (size_t)i * NB,
            fW2T + (size_t)i * NB * NB, filt_b2 + (size_t)i * NB,
            xf_buf, agg);
        if (i < 5) {
            node_fused_mfma<<<nblk_atom64, 128, 0, stream>>>(
                agg, oW1T + (size_t)i * NB * NB, f2out_b1 + (size_t)i * NB,
                oW2T + (size_t)i * NB * NB, f2out_b2 + (size_t)i * NB,
                in2f_WT + (size_t)(i + 1) * NB * NB,
                x_buf, xf_buf, N);
        } else {
            node_out_head_mfma<<<nblk_atom64, 256, 0, stream>>>(
                agg, oW1T + (size_t)i * NB * NB, f2out_b1 + (size_t)i * NB,
                oW2T + (size_t)i * NB * NB, f2out_b2 + (size_t)i * NB,
                x_buf, batch, hW1T, head_b1, head_W2,
                (float*)d_out, N);
        }
    }
}

// Round 12
// 2067.202 us; speedup vs baseline: 1.0679x; 1.0679x over previous
//
#include <hip/hip_runtime.h>
#include <hip/hip_bf16.h>
#include <math.h>

#define NB 128
#define NR 32
#define HPAD 136   // H/XA row stride in shorts (272B, 16B-aligned rows)
#define SCB 256    // scan blocks

// r27: edge = r24 2-subtile (confirmed 176us) + DIRECT A-FRAGMENT RBF:
// compute f_ij in registers in MFMA A-layout (d via __shfl, 8 exps/lane/
// subtile) instead of staging through fA LDS. Saves 10.2KB LDS (44->34.8KB
// -> 4 blk/CU, 12->16 waves/CU), one LDS roundtrip, one fence. r26's
// 4-subtile FALSIFIED (occupancy 31->11%, dur 175->233): weight-reuse
// lever pays only while concurrency preserved. Node kernels = r25.
// Confirmed: r22 fast scan (-150), r24 edge 2-subtile (-284), r25 node
// 2-subtile (-48). Falsified: r5/r6/r7/r10/r12/r14/r16/r17/r18/r20/r21/
// r26 (occupancy collapse).

static constexpr float CUTOFF_F    = 10.0f;
static constexpr float RBF_STEP    = 10.0f / 31.0f;
static constexpr float RBF_COEFF   = -4.805f;           // -0.5/(10/31)^2
static constexpr float LOG2_F      = 0.69314718055994531f;
static constexpr float PI_OVER_CUT = 0.314159265358979f;

typedef __attribute__((ext_vector_type(8))) short bf16x8;
typedef __attribute__((ext_vector_type(2))) short bf16x2;
typedef __attribute__((ext_vector_type(4))) float f32x4;

__device__ __forceinline__ short f2bs(float x) {
    __hip_bfloat16 h = __float2bfloat16(x);   // RNE
    return *reinterpret_cast<short*>(&h);
}
__device__ __forceinline__ float bs2f(unsigned short u) {
    unsigned int v = ((unsigned int)u) << 16;
    return __uint_as_float(v);
}
__device__ __forceinline__ float ssp_f(float v) {
    return fmaxf(v, 0.0f) + __logf(1.0f + __expf(-fabsf(v))) - LOG2_F;
}
__device__ __forceinline__ float silu_f(float v) {
    return v / (1.0f + __expf(-v));
}

// packed bf16 atomic add (2 features per op)
__device__ __forceinline__ void atomic_pk_add_bf16(short* addr, float lo, float hi) {
#if __has_builtin(__builtin_amdgcn_global_atomic_fadd_v2bf16)
    typedef bf16x2 __attribute__((address_space(1))) *gptr;
    bf16x2 v;
    v[0] = f2bs(lo);
    v[1] = f2bs(hi);
    __builtin_amdgcn_global_atomic_fadd_v2bf16((gptr)(unsigned long long)addr, v);
#else
    unsigned int* w = (unsigned int*)addr;
    unsigned int old = *w, assumed;
    do {
        assumed = old;
        float fl = bs2f((unsigned short)(assumed & 0xffff)) + lo;
        float fh = bs2f((unsigned short)(assumed >> 16)) + hi;
        unsigned int nv = ((unsigned int)(unsigned short)f2bs(fh) << 16) |
                          (unsigned short)f2bs(fl);
        old = atomicCAS(w, assumed, nv);
    } while (old != assumed);
#endif
}

// flush one merged run: 8 accumulated features/lane -> 4 pk atomics/lane.
// Run boundaries are quad-uniform so the lane^1 shuffles pair active lanes.
__device__ __forceinline__ void flush_pk(short* aggrow, const float* accum, int col) {
    bool even = ((col & 1) == 0);
#pragma unroll
    for (int q = 0; q < 4; q++) {
        float a = accum[2 * q], b = accum[2 * q + 1];
        float pa = __shfl_xor(a, 1);   // feature (2q)*16 + (col^1)
        float pb = __shfl_xor(b, 1);
        int nbase = even ? (2 * q) * 16 + col : (2 * q + 1) * 16 + (col - 1);
        float lo = even ? a : pb;
        float hi = even ? pa : b;
        atomic_pk_add_bf16(aggrow + nbase, lo, hi);
    }
}

// ---------------------------------------------------------------------------
// Weight prep: dst[b][c][r] = bf16(src[b][r][c])
// ---------------------------------------------------------------------------
__global__ void transpose_cvt(const float* __restrict__ src, short* __restrict__ dst,
                              int R, int C, int total) {
    int t = blockIdx.x * blockDim.x + threadIdx.x;
    if (t >= total) return;
    int rc = R * C;
    int b = t / rc;
    int rem = t - b * rc;
    int c = rem / R;
    int r = rem - c * R;
    dst[t] = f2bs(src[(size_t)b * rc + (size_t)r * C + c]);
}

// ---------------------------------------------------------------------------
// Edge prep: distances + per-atom histogram. 4 edges/thread for MLP.
// ---------------------------------------------------------------------------
__global__ void edge_prep4(const float* __restrict__ pos,
                           const int* __restrict__ idx_i,
                           const int* __restrict__ idx_j,
                           float* __restrict__ d_ij,
                           int* __restrict__ hist,
                           int E) {
    int b0 = blockIdx.x * 1024 + threadIdx.x;
    int ia[4], ib[4];
    bool val[4];
#pragma unroll
    for (int k = 0; k < 4; k++) {
        int e = b0 + k * 256;
        val[k] = (e < E);
        ia[k] = val[k] ? idx_i[e] : 0;
        ib[k] = val[k] ? idx_j[e] : 0;
    }
    float ax[4], ay[4], az[4], bx[4], by[4], bz[4];
#pragma unroll
    for (int k = 0; k < 4; k++) {
        const float* pa = pos + ia[k] * 3;
        ax[k] = pa[0]; ay[k] = pa[1]; az[k] = pa[2];
    }
#pragma unroll
    for (int k = 0; k < 4; k++) {
        const float* pb = pos + ib[k] * 3;
        bx[k] = pb[0]; by[k] = pb[1]; bz[k] = pb[2];
    }
#pragma unroll
    for (int k = 0; k < 4; k++) {
        if (!val[k]) continue;
        float dx = ax[k] - bx[k], dy = ay[k] - by[k], dz = az[k] - bz[k];
        float d = sqrtf(dx * dx + dy * dy + dz * dz);
        d_ij[b0 + k * 256] = d;
        if (d < CUTOFF_F) atomicAdd(&hist[ia[k]], 1);
    }
}

// ---------------------------------------------------------------------------
// Multi-block exclusive scan of hist[N] -> cursor[N]  (r22, ~12us).
// ---------------------------------------------------------------------------
__global__ __launch_bounds__(256) void scan_reduce(const int* __restrict__ hist,
                                                   int* __restrict__ partial, int N) {
    __shared__ int red[256];
    int b = blockIdx.x;
    int chunk = (N + SCB - 1) / SCB;
    int lo = b * chunk;
    int hi = min(lo + chunk, N);
    int s = 0;
    for (int i = lo + threadIdx.x; i < hi; i += 256) s += hist[i];
    red[threadIdx.x] = s;
    __syncthreads();
    for (int d = 128; d > 0; d >>= 1) {
        if (threadIdx.x < d) red[threadIdx.x] += red[threadIdx.x + d];
        __syncthreads();
    }
    if (threadIdx.x == 0) partial[b] = red[0];
}

__global__ __launch_bounds__(256) void scan_partials(int* __restrict__ partial) {
    __shared__ int sm[SCB];
    int t = threadIdx.x;
    sm[t] = partial[t];
    __syncthreads();
    for (int d = 1; d < SCB; d <<= 1) {
        int v = (t >= d) ? sm[t - d] : 0;
        __syncthreads();
        sm[t] += v;
        __syncthreads();
    }
    partial[t] = (t == 0) ? 0 : sm[t - 1];   // exclusive
}

__global__ __launch_bounds__(256) void scan_expand(const int* __restrict__ hist,
                                                   const int* __restrict__ partial,
                                                   int* __restrict__ cursor, int N) {
    __shared__ int tsum[256];
    int b = blockIdx.x;
    int chunk = (N + SCB - 1) / SCB;
    int lo = b * chunk;
    int hi = min(lo + chunk, N);
    int sub = (chunk + 255) / 256;
    int tlo = lo + threadIdx.x * sub;
    int thi = min(tlo + sub, hi);
    int s = 0;
    for (int i = tlo; i < thi; i++) s += hist[i];
    int t = threadIdx.x;
    tsum[t] = s;
    __syncthreads();
    for (int d = 1; d < 256; d <<= 1) {
        int v = (t >= d) ? tsum[t - d] : 0;
        __syncthreads();
        tsum[t] += v;
        __syncthreads();
    }
    int run = partial[b] + ((t == 0) ? 0 : tsum[t - 1]);
    for (int i = tlo; i < thi; i++) {
        cursor[i] = run;
        run += hist[i];
    }
}

// ---------------------------------------------------------------------------
// Scatter active edges into idx_i-grouped order. 4 edges/thread for MLP.
// Computes rcut for active edges only. After: cursor[a] == end of range.
// ---------------------------------------------------------------------------
__global__ void scatter_sorted4(const float* __restrict__ d_ij,
                                const int* __restrict__ idx_i,
                                const int* __restrict__ idx_j,
                                const int* __restrict__ edge_attr,
                                int* __restrict__ cursor,
                                float4* __restrict__ edata,
                                int* __restrict__ sIarr, int E) {
    int b0 = blockIdx.x * 1024 + threadIdx.x;
    float d[4]; int ii[4], jj[4], at[4]; bool act[4];
#pragma unroll
    for (int k = 0; k < 4; k++) {
        int e = b0 + k * 256;
        bool v = (e < E);
        d[k] = v ? d_ij[e] : 1e9f;
        act[k] = (d[k] < CUTOFF_F);
        ii[k] = act[k] ? idx_i[e] : 0;
        jj[k] = act[k] ? idx_j[e] : 0;
        at[k] = act[k] ? edge_attr[e] : 0;
    }
    int p[4];
#pragma unroll
    for (int k = 0; k < 4; k++)
        if (act[k]) p[k] = atomicAdd(&cursor[ii[k]], 1);
#pragma unroll
    for (int k = 0; k < 4; k++) {
        if (!act[k]) continue;
        float4 v;
        v.x = d[k];
        v.y = 0.5f * (__cosf(d[k] * PI_OVER_CUT) + 1.0f);
        v.z = __int_as_float(jj[k]);
        v.w = __int_as_float(at[k]);
        edata[p[k]] = v;
        sIarr[p[k]] = ii[k];
    }
}

// ---------------------------------------------------------------------------
// x = ele_emb[z] + res_emb[z_res]
// ---------------------------------------------------------------------------
__global__ void atom_embed(const int* __restrict__ z,
                           const int* __restrict__ z_res,
                           const float* __restrict__ ele_emb,
                           const float* __restrict__ res_emb,
                           float* __restrict__ x, int N) {
    int t = blockIdx.x * blockDim.x + threadIdx.x;
    if (t >= N * NB) return;
    int n = t >> 7, c = t & 127;
    x[t] = ele_emb[z[n] * NB + c] + res_emb[z_res[n] * NB + c];
}

// ---------------------------------------------------------------------------
// xf(bf16, permuted cols) = in(fp32) @ W  via MFMA. First-iteration in2f.
// ---------------------------------------------------------------------------
__global__ __launch_bounds__(256, 4) void node_in2f_mfma(
    const float* __restrict__ x, const short* __restrict__ WT,
    short* __restrict__ xf, int N) {
    __shared__ __align__(16) short XA[64 * HPAD];
    int a0 = blockIdx.x * 64;
    int t = threadIdx.x;
#pragma unroll
    for (int c = 0; c < 4; c++) {
        int chunk = t + c * 256;
        int row = chunk >> 4;
        int col = (chunk & 15) * 8;
        short v[8];
        if (a0 + row < N) {
            const float* src = x + (size_t)(a0 + row) * NB + col;
            float4 f0 = *(const float4*)src;
            float4 f1 = *(const float4*)(src + 4);
            v[0] = f2bs(f0.x); v[1] = f2bs(f0.y); v[2] = f2bs(f0.z); v[3] = f2bs(f0.w);
            v[4] = f2bs(f1.x); v[5] = f2bs(f1.y); v[6] = f2bs(f1.z); v[7] = f2bs(f1.w);
        } else {
#pragma unroll
            for (int j = 0; j < 8; j++) v[j] = 0;
        }
        *(bf16x8*)&XA[row * HPAD + col] = *(bf16x8*)v;
    }
    __syncthreads();

    int wid = t >> 6, lane = t & 63;
    int quad = lane >> 4, col = lane & 15;
    int mrow = wid * 16 + col;

    f32x4 acc[8] = {};
#pragma unroll
    for (int kt = 0; kt < 4; kt++) {
        bf16x8 a = *(bf16x8*)&XA[mrow * HPAD + kt * 32 + quad * 8];
#pragma unroll
        for (int nt = 0; nt < 8; nt++) {
            bf16x8 b = *(const bf16x8*)&WT[(nt * 16 + col) * NB + kt * 32 + quad * 8];
            acc[nt] = __builtin_amdgcn_mfma_f32_16x16x32_bf16(a, b, acc[nt], 0, 0, 0);
        }
    }
#pragma unroll
    for (int nt = 0; nt < 8; nt++) {
        int cst = col * 8 + nt;   // permuted storage col
#pragma unroll
        for (int r = 0; r < 4; r++) {
            int m = wid * 16 + quad * 4 + r;
            if (a0 + m < N) xf[(size_t)(a0 + m) * NB + cst] = f2bs(acc[nt][r]);
        }
    }
}

// ---------------------------------------------------------------------------
// 2-SUBTILE node_fused (r25, confirmed): v = ssp(agg@W1+b1)@W2+b2 ; x += v ;
// xf_next(bf16, permuted) = x @ Wn. 128 threads / 2 waves per 64-atom
// block; per-kt weight fragments loaded once per wave, consumed by both
// subtiles. Staging wave-local -> barrier-free. Re-zeroes its agg rows.
// ---------------------------------------------------------------------------
__global__ __launch_bounds__(128, 1) void node_fused_mfma(
    short* __restrict__ agg,
    const short* __restrict__ W1T, const float* __restrict__ b1,
    const short* __restrict__ W2T, const float* __restrict__ b2,
    const short* __restrict__ WnT,
    float* __restrict__ x, short* __restrict__ xf, int N) {
    __shared__ __align__(16) short XA[64 * HPAD];
    __shared__ __align__(16) short H[64 * HPAD];
    int a0 = blockIdx.x * 64;
    int t = threadIdx.x;                 // [0,128)
    int wid = t >> 6, lane = t & 63;     // 2 waves
    int quad = lane >> 4, col = lane & 15;

    // wave-local staging: wave wid stages its own rows [wid*32, wid*32+32)
#pragma unroll
    for (int c = 0; c < 8; c++) {
        int chunk = lane + c * 64;            // [0,512)
        int row = wid * 32 + (chunk >> 4);    // wave-local row
        int colb = (chunk & 15) * 8;
        bf16x8 v = {0, 0, 0, 0, 0, 0, 0, 0};
        if (a0 + row < N) {
            short* src = agg + (size_t)(a0 + row) * NB + colb;
            v = *(const bf16x8*)src;
            *(bf16x8*)src = (bf16x8){0, 0, 0, 0, 0, 0, 0, 0};  // re-zero
        }
        *(bf16x8*)&XA[row * HPAD + colb] = v;
    }
    asm volatile("s_waitcnt lgkmcnt(0)" ::: "memory");
    __builtin_amdgcn_sched_barrier(0);

    // GEMM1 + ssp -> H (2 subtiles, weights loaded once per kt)
    {
        f32x4 acc[2][8] = {};
#pragma unroll
        for (int kt = 0; kt < 4; kt++) {
            bf16x8 bf[8];
#pragma unroll
            for (int nt = 0; nt < 8; nt++)
                bf[nt] = *(const bf16x8*)&W1T[(nt * 16 + col) * NB + kt * 32 + quad * 8];
#pragma unroll
            for (int s = 0; s < 2; s++) {
                bf16x8 a = *(bf16x8*)&XA[(wid * 32 + s * 16 + col) * HPAD + kt * 32 + quad * 8];
#pragma unroll
                for (int nt = 0; nt < 8; nt++)
                    acc[s][nt] = __builtin_amdgcn_mfma_f32_16x16x32_bf16(a, bf[nt], acc[s][nt], 0, 0, 0);
            }
        }
#pragma unroll
        for (int s = 0; s < 2; s++) {
#pragma unroll
            for (int nt = 0; nt < 8; nt++) {
                int n = nt * 16 + col;
                float bias = b1[n];
#pragma unroll
                for (int r = 0; r < 4; r++) {
                    int m = wid * 32 + s * 16 + quad * 4 + r;
                    H[m * HPAD + n] = f2bs(ssp_f(acc[s][nt][r] + bias));
                }
            }
        }
    }
    asm volatile("s_waitcnt lgkmcnt(0)" ::: "memory");
    __builtin_amdgcn_sched_barrier(0);

    // GEMM2 + residual: x_new -> global fp32 + XA bf16 (reuse)
    {
        f32x4 acc[2][8] = {};
#pragma unroll
        for (int kt = 0; kt < 4; kt++) {
            bf16x8 bf[8];
#pragma unroll
            for (int nt = 0; nt < 8; nt++)
                bf[nt] = *(const bf16x8*)&W2T[(nt * 16 + col) * NB + kt * 32 + quad * 8];
#pragma unroll
            for (int s = 0; s < 2; s++) {
                bf16x8 a = *(bf16x8*)&H[(wid * 32 + s * 16 + col) * HPAD + kt * 32 + quad * 8];
#pragma unroll
                for (int nt = 0; nt < 8; nt++)
                    acc[s][nt] = __builtin_amdgcn_mfma_f32_16x16x32_bf16(a, bf[nt], acc[s][nt], 0, 0, 0);
            }
        }
#pragma unroll
        for (int s = 0; s < 2; s++) {
#pragma unroll
            for (int nt = 0; nt < 8; nt++) {
                int n = nt * 16 + col;
                float bias = b2[n];
#pragma unroll
                for (int r = 0; r < 4; r++) {
                    int m = wid * 32 + s * 16 + quad * 4 + r;
                    float xn = 0.0f;
                    if (a0 + m < N) {
                        size_t o = (size_t)(a0 + m) * NB + n;
                        xn = x[o] + acc[s][nt][r] + bias;
                        x[o] = xn;
                    }
                    XA[m * HPAD + n] = f2bs(xn);
                }
            }
        }
    }
    asm volatile("s_waitcnt lgkmcnt(0)" ::: "memory");
    __builtin_amdgcn_sched_barrier(0);

    // GEMM3: xf = x_new @ Wn  (bf16 out, permuted storage cols)
    {
        f32x4 acc[2][8] = {};
#pragma unroll
        for (int kt = 0; kt < 4; kt++) {
            bf16x8 bf[8];
#pragma unroll
            for (int nt = 0; nt < 8; nt++)
                bf[nt] = *(const bf16x8*)&WnT[(nt * 16 + col) * NB + kt * 32 + quad * 8];
#pragma unroll
            for (int s = 0; s < 2; s++) {
                bf16x8 a = *(bf16x8*)&XA[(wid * 32 + s * 16 + col) * HPAD + kt * 32 + quad * 8];
#pragma unroll
                for (int nt = 0; nt < 8; nt++)
                    acc[s][nt] = __builtin_amdgcn_mfma_f32_16x16x32_bf16(a, bf[nt], acc[s][nt], 0, 0, 0);
            }
        }
#pragma unroll
        for (int s = 0; s < 2; s++) {
#pragma unroll
            for (int nt = 0; nt < 8; nt++) {
                int cst = col * 8 + nt;
#pragma unroll
                for (int r = 0; r < 4; r++) {
                    int m = wid * 32 + s * 16 + quad * 4 + r;
                    if (a0 + m < N) xf[(size_t)(a0 + m) * NB + cst] = f2bs(acc[s][nt][r]);
                }
            }
        }
    }
}

// ---------------------------------------------------------------------------
// Last iteration fused with head: v = ssp(agg@W1+b1)@W2+b2 ; xn = x + v ;
// h = silu(xn/||xn||) ; silu(h@hW1+hb1)@hW2 ; segment-sum by batch.
// ---------------------------------------------------------------------------
__global__ __launch_bounds__(256, 4) void node_out_head_mfma(
    const short* __restrict__ agg,
    const short* __restrict__ W1T, const float* __restrict__ b1,
    const short* __restrict__ W2T, const float* __restrict__ b2,
    const float* __restrict__ x, const int* __restrict__ batch,
    const short* __restrict__ hW1T, const float* __restrict__ hb1,
    const float* __restrict__ hW2,
    float* __restrict__ out, int N) {
    __shared__ __align__(16) short XA[64 * HPAD];
    __shared__ __align__(16) short H[64 * HPAD];
    __shared__ int sbat[64];
    __shared__ float rowval[64];
    int a0 = blockIdx.x * 64;
    int t = threadIdx.x;

    if (t < 64) sbat[t] = (a0 + t < N) ? batch[a0 + t] : -1;
#pragma unroll
    for (int c = 0; c < 4; c++) {
        int chunk = t + c * 256;
        int row = chunk >> 4;
        int col = (chunk & 15) * 8;
        bf16x8 v = {0, 0, 0, 0, 0, 0, 0, 0};
        if (a0 + row < N) v = *(const bf16x8*)&agg[(size_t)(a0 + row) * NB + col];
        *(bf16x8*)&XA[row * HPAD + col] = v;
    }
    __syncthreads();

    int wid = t >> 6, lane = t & 63;
    int quad = lane >> 4, col = lane & 15;
    int mrow = wid * 16 + col;

    // GEMM1 + ssp -> H
    {
        f32x4 acc[8] = {};
#pragma unroll
        for (int kt = 0; kt < 4; kt++) {
            bf16x8 a = *(bf16x8*)&XA[mrow * HPAD + kt * 32 + quad * 8];
#pragma unroll
            for (int nt = 0; nt < 8; nt++) {
                bf16x8 b = *(const bf16x8*)&W1T[(nt * 16 + col) * NB + kt * 32 + quad * 8];
                acc[nt] = __builtin_amdgcn_mfma_f32_16x16x32_bf16(a, b, acc[nt], 0, 0, 0);
            }
        }
#pragma unroll
        for (int nt = 0; nt < 8; nt++) {
            int n = nt * 16 + col;
            float bias = b1[n];
#pragma unroll
            for (int r = 0; r < 4; r++) {
                int m = wid * 16 + quad * 4 + r;
                H[m * HPAD + n] = f2bs(ssp_f(acc[nt][r] + bias));
            }
        }
    }
    __syncthreads();

    // GEMM2 + residual in registers; row sums of squares via 16-lane shuffle
    float xnv[8][4];
    float ssq[4] = {0.f, 0.f, 0.f, 0.f};
    {
        f32x4 acc[8] = {};
#pragma unroll
        for (int kt = 0; kt < 4; kt++) {
            bf16x8 a = *(bf16x8*)&H[mrow * HPAD + kt * 32 + quad * 8];
#pragma unroll
            for (int nt = 0; nt < 8; nt++) {
                bf16x8 b = *(const bf16x8*)&W2T[(nt * 16 + col) * NB + kt * 32 + quad * 8];
                acc[nt] = __builtin_amdgcn_mfma_f32_16x16x32_bf16(a, b, acc[nt], 0, 0, 0);
            }
        }
#pragma unroll
        for (int nt = 0; nt < 8; nt++) {
            int n = nt * 16 + col;
            float bias = b2[n];
#pragma unroll
            for (int r = 0; r < 4; r++) {
                int m = wid * 16 + quad * 4 + r;
                float xn = 0.0f;
                if (a0 + m < N) xn = x[(size_t)(a0 + m) * NB + n] + acc[nt][r] + bias;
                xnv[nt][r] = xn;
                ssq[r] += xn * xn;
            }
        }
    }
#pragma unroll
    for (int r = 0; r < 4; r++) {
#pragma unroll
        for (int m = 1; m < 16; m <<= 1) ssq[r] += __shfl_xor(ssq[r], m);
    }
    float inv[4];
#pragma unroll
    for (int r = 0; r < 4; r++) inv[r] = 1.0f / fmaxf(sqrtf(ssq[r]), 1e-12f);
    __syncthreads();
#pragma unroll
    for (int nt = 0; nt < 8; nt++) {
        int n = nt * 16 + col;
#pragma unroll
        for (int r = 0; r < 4; r++) {
            int m = wid * 16 + quad * 4 + r;
            XA[m * HPAD + n] = f2bs(silu_f(xnv[nt][r] * inv[r]));
        }
    }
    __syncthreads();

    // head GEMM: silu(h@hW1+hb1) dot hW2 per row
    f32x4 acc[8] = {};
#pragma unroll
    for (int kt = 0; kt < 4; kt++) {
        bf16x8 a = *(bf16x8*)&XA[mrow * HPAD + kt * 32 + quad * 8];
#pragma unroll
        for (int nt = 0; nt < 8; nt++) {
            bf16x8 b = *(const bf16x8*)&hW1T[(nt * 16 + col) * NB + kt * 32 + quad * 8];
            acc[nt] = __builtin_amdgcn_mfma_f32_16x16x32_bf16(a, b, acc[nt], 0, 0, 0);
        }
    }
    float partial[4] = {0.f, 0.f, 0.f, 0.f};
#pragma unroll
    for (int nt = 0; nt < 8; nt++) {
        int n = nt * 16 + col;
        float bias = hb1[n];
        float w2 = hW2[n];
#pragma unroll
        for (int r = 0; r < 4; r++) partial[r] += silu_f(acc[nt][r] + bias) * w2;
    }
#pragma unroll
    for (int r = 0; r < 4; r++) {
#pragma unroll
        for (int d = 1; d < 16; d <<= 1) partial[r] += __shfl_xor(partial[r], d);
    }
    if (col == 0) {
#pragma unroll
        for (int r = 0; r < 4; r++) rowval[wid * 16 + quad * 4 + r] = partial[r];
    }
    __syncthreads();

    if (t < 64) {
        int b = sbat[t];
        bool headf = (b >= 0) && (t == 0 || sbat[t - 1] != b);
        if (headf) {
            float s = 0.0f;
            int rr = t;
            while (rr < 64 && sbat[rr] == b) { s += rowval[rr]; rr++; }
            atomicAdd(&out[b], s);
        }
    }
}

// ---------------------------------------------------------------------------
// BARRIER-FREE 2-subtile edge kernel + DIRECT A-FRAGMENT RBF (r27).
// 128 edges/block, 4 waves, each wave owns 32 contiguous edges as two M=16
// subtiles. f_ij computed in registers in MFMA A-layout (no fA LDS, no
// first fence): lane (quad,col) of subtile s needs f[s*16+col][quad*8..+8].
// Weight fragments loaded once per wave, reused by both subtiles. LDS
// 34.8KB -> 4 blk/CU (16 waves/CU vs 12 in r24).
// ---------------------------------------------------------------------------
__global__ __launch_bounds__(256, 4) void edge_fused_mfma(
    const float4* __restrict__ edata, const int* __restrict__ sIarr,
    const int* __restrict__ rowend, int natoms,
    const float* __restrict__ edge_emb,
    const short* __restrict__ W1T, const float* __restrict__ b1,
    const short* __restrict__ W2T, const float* __restrict__ b2,
    const short* __restrict__ xf, short* __restrict__ agg) {
    __shared__ __align__(16) short H[128 * HPAD];

    int t = threadIdx.x;
    int wid = t >> 6, lane = t & 63;
    int quad = lane >> 4, col = lane & 15;
    int base = blockIdx.x * 128;
    int wbase = base + wid * 32;        // this wave's 32-edge window
    int el32 = lane & 31;               // lane holds record of edge wbase+el32

    // issue record loads immediately (edata/sIarr are E-sized)
    float4 ed = edata[wbase + el32];
    int sIv0 = sIarr[wbase + el32];
    int cnt = rowend[natoms - 1];
    if (base >= cnt) return;

    bool act = (wbase + el32) < cnt;
    float dv  = act ? ed.x : 1e9f;
    float rcv = act ? ed.y : 0.0f;
    int   jjv = act ? __float_as_int(ed.z) : 0;
    int   atv = act ? __float_as_int(ed.w) : 0;
    int   iiv = act ? sIv0 : 0;

    // gathers for both subtiles (permuted xf): one bf16x8 per edge.
    // Latency hides under GEMM1 + ssp + H staging + GEMM2.
    bf16x8 xv[2][4];
    const unsigned short* xg = (const unsigned short*)xf;
#pragma unroll
    for (int s = 0; s < 2; s++) {
#pragma unroll
        for (int r = 0; r < 4; r++) {
            int jj = __shfl(jjv, s * 16 + quad * 4 + r);
            xv[s][r] = *(const bf16x8*)&xg[(size_t)jj * NB + col * 8];
        }
    }

    // GEMM1: hidden = f_ij @ W1 (K=32). A-fragments computed DIRECTLY in
    // registers (f[s*16+col][quad*8+j]); weights loaded once for 2 subtiles.
    {
        bf16x8 b1f[8];
#pragma unroll
        for (int nt = 0; nt < 8; nt++)
            b1f[nt] = *(const bf16x8*)&W1T[(nt * 16 + col) * NR + quad * 8];
#pragma unroll
        for (int s = 0; s < 2; s++) {
            int erow = s * 16 + col;                 // wave-local edge
            float d  = __shfl(dv, erow);
            int   at = __shfl(atv, erow);
            const float* em = edge_emb + at * NR + quad * 8;
            short av[8];
#pragma unroll
            for (int j = 0; j < 8; j++) {
                float off = (float)(quad * 8 + j) * RBF_STEP;
                float dd = d - off;
                av[j] = f2bs(__expf(RBF_COEFF * dd * dd) + em[j]);
            }
            bf16x8 a1 = *(bf16x8*)av;
            f32x4 acc[8];
#pragma unroll
            for (int nt = 0; nt < 8; nt++)
                acc[nt] = __builtin_amdgcn_mfma_f32_16x16x32_bf16(a1, b1f[nt], (f32x4){0.f, 0.f, 0.f, 0.f}, 0, 0, 0);
#pragma unroll
            for (int nt = 0; nt < 8; nt++) {
                int n = nt * 16 + col;
                float bias = b1[n];
#pragma unroll
                for (int r = 0; r < 4; r++) {
                    int m = wid * 32 + s * 16 + quad * 4 + r;
                    H[m * HPAD + n] = f2bs(ssp_f(acc[nt][r] + bias));
                }
            }
        }
    }

    // wave-local LDS fence: H writes -> GEMM2 reads
    asm volatile("s_waitcnt lgkmcnt(0)" ::: "memory");
    __builtin_amdgcn_sched_barrier(0);

    // GEMM2: Wij = hidden @ W2 (K=128); each kt's B-fragments loaded ONCE
    // and consumed by both subtiles (halves W2T traffic).
    f32x4 acc2[2][8] = {};
#pragma unroll
    for (int kt = 0; kt < 4; kt++) {
        bf16x8 b2f[8];
#pragma unroll
        for (int nt = 0; nt < 8; nt++)
            b2f[nt] = *(const bf16x8*)&W2T[(nt * 16 + col) * NB + kt * 32 + quad * 8];
#pragma unroll
        for (int s = 0; s < 2; s++) {
            bf16x8 a = *(bf16x8*)&H[(wid * 32 + s * 16 + col) * HPAD + kt * 32 + quad * 8];
#pragma unroll
            for (int nt = 0; nt < 8; nt++)
                acc2[s][nt] = __builtin_amdgcn_mfma_f32_16x16x32_bf16(a, b2f[nt], acc2[s][nt], 0, 0, 0);
        }
    }

    // epilogue: per subtile, merge equal-atom runs over the quad's 4 edges,
    // flush merged runs with pk atomics (quad-uniform branches).
    float b2v[8];
#pragma unroll
    for (int nt = 0; nt < 8; nt++) b2v[nt] = b2[nt * 16 + col];

#pragma unroll
    for (int s = 0; s < 2; s++) {
        int e0l = s * 16 + quad * 4;
        int cur = __shfl(iiv, e0l);
        float accum[8] = {0.f, 0.f, 0.f, 0.f, 0.f, 0.f, 0.f, 0.f};
#pragma unroll
        for (int r = 0; r < 4; r++) {
            int ii = __shfl(iiv, e0l + r);
            float rc = __shfl(rcv, e0l + r);
            if (ii != cur) {
                flush_pk(agg + (size_t)cur * NB, accum, col);
#pragma unroll
                for (int nt = 0; nt < 8; nt++) accum[nt] = 0.f;
                cur = ii;
            }
#pragma unroll
            for (int nt = 0; nt < 8; nt++) {
                float w = (acc2[s][nt][r] + b2v[nt]) * rc;
                accum[nt] = fmaf(w, bs2f((unsigned short)xv[s][r][nt]), accum[nt]);
            }
        }
        flush_pk(agg + (size_t)cur * NB, accum, col);
    }
}

// ---------------------------------------------------------------------------
extern "C" void kernel_launch(void* const* d_in, const int* in_sizes, int n_in,
                              void* d_out, int out_size, void* d_ws, size_t ws_size,
                              hipStream_t stream) {
    const int*   z        = (const int*)d_in[0];
    const int*   z_res    = (const int*)d_in[1];
    const float* pos      = (const float*)d_in[2];
    const int*   idx_i    = (const int*)d_in[3];
    const int*   idx_j    = (const int*)d_in[4];
    const int*   edge_attr= (const int*)d_in[5];
    const int*   batch    = (const int*)d_in[6];
    const float* ele_emb  = (const float*)d_in[7];
    const float* res_emb  = (const float*)d_in[8];
    const float* edge_emb = (const float*)d_in[9];
    const float* in2f_W   = (const float*)d_in[10];
    const float* filt_W1  = (const float*)d_in[11];
    const float* filt_b1  = (const float*)d_in[12];
    const float* filt_W2  = (const float*)d_in[13];
    const float* filt_b2  = (const float*)d_in[14];
    const float* f2out_W1 = (const float*)d_in[15];
    const float* f2out_b1 = (const float*)d_in[16];
    const float* f2out_W2 = (const float*)d_in[17];
    const float* f2out_b2 = (const float*)d_in[18];
    const float* head_W1  = (const float*)d_in[19];
    const float* head_b1  = (const float*)d_in[20];
    const float* head_W2  = (const float*)d_in[21];

    const int N = in_sizes[0];
    const int E = in_sizes[3];

    char* p = (char*)d_ws;
    size_t off = 0;
    auto carve = [&](size_t bytes) -> void* {
        void* q = p + off;
        off = (off + bytes + 255) & ~(size_t)255;
        return q;
    };
    float*  d_d      = (float*)carve((size_t)E * 4);
    float4* edata    = (float4*)carve((size_t)E * 16);
    int*    sIarr    = (int*)carve((size_t)E * 4);
    int*    hist     = (int*)carve((size_t)N * 4);
    int*    cursor   = (int*)carve((size_t)N * 4);
    int*    partial  = (int*)carve((size_t)SCB * 4);
    float*  x_buf    = (float*)carve((size_t)N * NB * 4);
    short*  xf_buf   = (short*)carve((size_t)N * NB * 2);
    short*  agg      = (short*)carve((size_t)N * NB * 2);
    short*  in2f_WT  = (short*)carve((size_t)6 * NB * NB * 2);
    short*  fW1T     = (short*)carve((size_t)6 * NR * NB * 2);
    short*  fW2T     = (short*)carve((size_t)6 * NB * NB * 2);
    short*  oW1T     = (short*)carve((size_t)6 * NB * NB * 2);
    short*  oW2T     = (short*)carve((size_t)6 * NB * NB * 2);
    short*  hW1T     = (short*)carve((size_t)NB * NB * 2);
    (void)ws_size;

    // weight prep (bf16 transposed)
    {
        int tot = 6 * NB * NB;
        transpose_cvt<<<(tot + 255) / 256, 256, 0, stream>>>(in2f_W, in2f_WT, NB, NB, tot);
        transpose_cvt<<<(tot + 255) / 256, 256, 0, stream>>>(filt_W2, fW2T, NB, NB, tot);
        transpose_cvt<<<(tot + 255) / 256, 256, 0, stream>>>(f2out_W1, oW1T, NB, NB, tot);
        transpose_cvt<<<(tot + 255) / 256, 256, 0, stream>>>(f2out_W2, oW2T, NB, NB, tot);
        int tot1 = 6 * NR * NB;
        transpose_cvt<<<(tot1 + 255) / 256, 256, 0, stream>>>(filt_W1, fW1T, NR, NB, tot1);
        int tot2 = NB * NB;
        transpose_cvt<<<(tot2 + 255) / 256, 256, 0, stream>>>(head_W1, hW1T, NB, NB, tot2);
    }

    // edge prep + idx_i-grouped sort with packed records
    hipMemsetAsync(hist, 0, (size_t)N * 4, stream);
    int nblk_e4 = (E + 1023) / 1024;
    edge_prep4<<<nblk_e4, 256, 0, stream>>>(pos, idx_i, idx_j, d_d, hist, E);
    // multi-block exclusive scan: hist -> cursor (r22)
    scan_reduce<<<SCB, 256, 0, stream>>>(hist, partial, N);
    scan_partials<<<1, SCB, 0, stream>>>(partial);
    scan_expand<<<SCB, 256, 0, stream>>>(hist, partial, cursor, N);
    scatter_sorted4<<<nblk_e4, 256, 0, stream>>>(d_d, idx_i, idx_j, edge_attr,
                                                 cursor, edata, sIarr, E);
    // cursor[a] is now the END of atom a's sorted range; cursor[N-1] = count.

    atom_embed<<<(N * NB + 255) / 256, 256, 0, stream>>>(z, z_res, ele_emb, res_emb, x_buf, N);

    int nblk_atom64 = (N + 63) / 64;
    int nblk_edge = (E + 127) / 128;

    node_in2f_mfma<<<nblk_atom64, 256, 0, stream>>>(x_buf, in2f_WT, xf_buf, N);
    hipMemsetAsync(d_out, 0, (size_t)out_size * sizeof(float), stream);
    hipMemsetAsync(agg, 0, (size_t)N * NB * 2, stream);   // once; node_fused re-zeroes
    for (int i = 0; i < 6; i++) {
        edge_fused_mfma<<<nblk_edge, 256, 0, stream>>>(
            edata, sIarr, cursor, N, edge_emb,
            fW1T + (size_t)i * NR * NB, filt_b1 + (size_t)i * NB,
            fW2T + (size_t)i * NB * NB, filt_b2 + (size_t)i * NB,
            xf_buf, agg);
        if (i < 5) {
            node_fused_mfma<<<nblk_atom64, 128, 0, stream>>>(
                agg, oW1T + (size_t)i * NB * NB, f2out_b1 + (size_t)i * NB,
                oW2T + (size_t)i * NB * NB, f2out_b2 + (size_t)i * NB,
                in2f_WT + (size_t)(i + 1) * NB * NB,
                x_buf, xf_buf, N);
        } else {
            node_out_head_mfma<<<nblk_atom64, 256, 0, stream>>>(
                agg, oW1T + (size_t)i * NB * NB, f2out_b1 + (size_t)i * NB,
                oW2T + (size_t)i * NB * NB, f2out_b2 + (size_t)i * NB,
                x_buf, batch, hW1T, head_b1, head_W2,
                (float*)d_out, N);
        }
    }
}

// Round 13
// 1938.436 us; speedup vs baseline: 1.1388x; 1.0664x over previous
//
#include <hip/hip_runtime.h>
#include <hip/hip_bf16.h>
#include <math.h>

#define NB 128
#define NR 32
#define HPAD 136   // H/XA row stride in shorts (272B, 16B-aligned rows)
#define SCB 256    // scan blocks

// r28: r27 edge (direct A-fragment RBF, no fA LDS) + __launch_bounds__
// (256,3) to cap edge occupancy at 3 blk/CU. r27 FALSIFIED occupancy-
// as-free: LDS cut let 4 blk/CU run -> concurrent edge window grew ->
// agg-atomic + xf-gather working set blew L2 -> FETCH 93->221MB, WRITE
// 168->386MB, dur 175->215. Same mechanism as r14. r28 keeps direct-RBF
// wins (no fA roundtrip, one fewer fence) at r24's proven concurrency.
// Node kernels = r25. Confirmed: r22 fast scan (-150), r24 edge 2-subtile
// (-284), r25 node 2-subtile (-48). Falsified: r5/r6/r7/r10/r12/r14/r16/
// r17/r18/r20/r21/r26 (occupancy collapse)/r27-unbounded (L2 thrash).

static constexpr float CUTOFF_F    = 10.0f;
static constexpr float RBF_STEP    = 10.0f / 31.0f;
static constexpr float RBF_COEFF   = -4.805f;           // -0.5/(10/31)^2
static constexpr float LOG2_F      = 0.69314718055994531f;
static constexpr float PI_OVER_CUT = 0.314159265358979f;

typedef __attribute__((ext_vector_type(8))) short bf16x8;
typedef __attribute__((ext_vector_type(2))) short bf16x2;
typedef __attribute__((ext_vector_type(4))) float f32x4;

__device__ __forceinline__ short f2bs(float x) {
    __hip_bfloat16 h = __float2bfloat16(x);   // RNE
    return *reinterpret_cast<short*>(&h);
}
__device__ __forceinline__ float bs2f(unsigned short u) {
    unsigned int v = ((unsigned int)u) << 16;
    return __uint_as_float(v);
}
__device__ __forceinline__ float ssp_f(float v) {
    return fmaxf(v, 0.0f) + __logf(1.0f + __expf(-fabsf(v))) - LOG2_F;
}
__device__ __forceinline__ float silu_f(float v) {
    return v / (1.0f + __expf(-v));
}

// packed bf16 atomic add (2 features per op)
__device__ __forceinline__ void atomic_pk_add_bf16(short* addr, float lo, float hi) {
#if __has_builtin(__builtin_amdgcn_global_atomic_fadd_v2bf16)
    typedef bf16x2 __attribute__((address_space(1))) *gptr;
    bf16x2 v;
    v[0] = f2bs(lo);
    v[1] = f2bs(hi);
    __builtin_amdgcn_global_atomic_fadd_v2bf16((gptr)(unsigned long long)addr, v);
#else
    unsigned int* w = (unsigned int*)addr;
    unsigned int old = *w, assumed;
    do {
        assumed = old;
        float fl = bs2f((unsigned short)(assumed & 0xffff)) + lo;
        float fh = bs2f((unsigned short)(assumed >> 16)) + hi;
        unsigned int nv = ((unsigned int)(unsigned short)f2bs(fh) << 16) |
                          (unsigned short)f2bs(fl);
        old = atomicCAS(w, assumed, nv);
    } while (old != assumed);
#endif
}

// flush one merged run: 8 accumulated features/lane -> 4 pk atomics/lane.
// Run boundaries are quad-uniform so the lane^1 shuffles pair active lanes.
__device__ __forceinline__ void flush_pk(short* aggrow, const float* accum, int col) {
    bool even = ((col & 1) == 0);
#pragma unroll
    for (int q = 0; q < 4; q++) {
        float a = accum[2 * q], b = accum[2 * q + 1];
        float pa = __shfl_xor(a, 1);   // feature (2q)*16 + (col^1)
        float pb = __shfl_xor(b, 1);
        int nbase = even ? (2 * q) * 16 + col : (2 * q + 1) * 16 + (col - 1);
        float lo = even ? a : pb;
        float hi = even ? pa : b;
        atomic_pk_add_bf16(aggrow + nbase, lo, hi);
    }
}

// ---------------------------------------------------------------------------
// Weight prep: dst[b][c][r] = bf16(src[b][r][c])
// ---------------------------------------------------------------------------
__global__ void transpose_cvt(const float* __restrict__ src, short* __restrict__ dst,
                              int R, int C, int total) {
    int t = blockIdx.x * blockDim.x + threadIdx.x;
    if (t >= total) return;
    int rc = R * C;
    int b = t / rc;
    int rem = t - b * rc;
    int c = rem / R;
    int r = rem - c * R;
    dst[t] = f2bs(src[(size_t)b * rc + (size_t)r * C + c]);
}

// ---------------------------------------------------------------------------
// Edge prep: distances + per-atom histogram. 4 edges/thread for MLP.
// ---------------------------------------------------------------------------
__global__ void edge_prep4(const float* __restrict__ pos,
                           const int* __restrict__ idx_i,
                           const int* __restrict__ idx_j,
                           float* __restrict__ d_ij,
                           int* __restrict__ hist,
                           int E) {
    int b0 = blockIdx.x * 1024 + threadIdx.x;
    int ia[4], ib[4];
    bool val[4];
#pragma unroll
    for (int k = 0; k < 4; k++) {
        int e = b0 + k * 256;
        val[k] = (e < E);
        ia[k] = val[k] ? idx_i[e] : 0;
        ib[k] = val[k] ? idx_j[e] : 0;
    }
    float ax[4], ay[4], az[4], bx[4], by[4], bz[4];
#pragma unroll
    for (int k = 0; k < 4; k++) {
        const float* pa = pos + ia[k] * 3;
        ax[k] = pa[0]; ay[k] = pa[1]; az[k] = pa[2];
    }
#pragma unroll
    for (int k = 0; k < 4; k++) {
        const float* pb = pos + ib[k] * 3;
        bx[k] = pb[0]; by[k] = pb[1]; bz[k] = pb[2];
    }
#pragma unroll
    for (int k = 0; k < 4; k++) {
        if (!val[k]) continue;
        float dx = ax[k] - bx[k], dy = ay[k] - by[k], dz = az[k] - bz[k];
        float d = sqrtf(dx * dx + dy * dy + dz * dz);
        d_ij[b0 + k * 256] = d;
        if (d < CUTOFF_F) atomicAdd(&hist[ia[k]], 1);
    }
}

// ---------------------------------------------------------------------------
// Multi-block exclusive scan of hist[N] -> cursor[N]  (r22, ~12us).
// ---------------------------------------------------------------------------
__global__ __launch_bounds__(256) void scan_reduce(const int* __restrict__ hist,
                                                   int* __restrict__ partial, int N) {
    __shared__ int red[256];
    int b = blockIdx.x;
    int chunk = (N + SCB - 1) / SCB;
    int lo = b * chunk;
    int hi = min(lo + chunk, N);
    int s = 0;
    for (int i = lo + threadIdx.x; i < hi; i += 256) s += hist[i];
    red[threadIdx.x] = s;
    __syncthreads();
    for (int d = 128; d > 0; d >>= 1) {
        if (threadIdx.x < d) red[threadIdx.x] += red[threadIdx.x + d];
        __syncthreads();
    }
    if (threadIdx.x == 0) partial[b] = red[0];
}

__global__ __launch_bounds__(256) void scan_partials(int* __restrict__ partial) {
    __shared__ int sm[SCB];
    int t = threadIdx.x;
    sm[t] = partial[t];
    __syncthreads();
    for (int d = 1; d < SCB; d <<= 1) {
        int v = (t >= d) ? sm[t - d] : 0;
        __syncthreads();
        sm[t] += v;
        __syncthreads();
    }
    partial[t] = (t == 0) ? 0 : sm[t - 1];   // exclusive
}

__global__ __launch_bounds__(256) void scan_expand(const int* __restrict__ hist,
                                                   const int* __restrict__ partial,
                                                   int* __restrict__ cursor, int N) {
    __shared__ int tsum[256];
    int b = blockIdx.x;
    int chunk = (N + SCB - 1) / SCB;
    int lo = b * chunk;
    int hi = min(lo + chunk, N);
    int sub = (chunk + 255) / 256;
    int tlo = lo + threadIdx.x * sub;
    int thi = min(tlo + sub, hi);
    int s = 0;
    for (int i = tlo; i < thi; i++) s += hist[i];
    int t = threadIdx.x;
    tsum[t] = s;
    __syncthreads();
    for (int d = 1; d < 256; d <<= 1) {
        int v = (t >= d) ? tsum[t - d] : 0;
        __syncthreads();
        tsum[t] += v;
        __syncthreads();
    }
    int run = partial[b] + ((t == 0) ? 0 : tsum[t - 1]);
    for (int i = tlo; i < thi; i++) {
        cursor[i] = run;
        run += hist[i];
    }
}

// ---------------------------------------------------------------------------
// Scatter active edges into idx_i-grouped order. 4 edges/thread for MLP.
// Computes rcut for active edges only. After: cursor[a] == end of range.
// ---------------------------------------------------------------------------
__global__ void scatter_sorted4(const float* __restrict__ d_ij,
                                const int* __restrict__ idx_i,
                                const int* __restrict__ idx_j,
                                const int* __restrict__ edge_attr,
                                int* __restrict__ cursor,
                                float4* __restrict__ edata,
                                int* __restrict__ sIarr, int E) {
    int b0 = blockIdx.x * 1024 + threadIdx.x;
    float d[4]; int ii[4], jj[4], at[4]; bool act[4];
#pragma unroll
    for (int k = 0; k < 4; k++) {
        int e = b0 + k * 256;
        bool v = (e < E);
        d[k] = v ? d_ij[e] : 1e9f;
        act[k] = (d[k] < CUTOFF_F);
        ii[k] = act[k] ? idx_i[e] : 0;
        jj[k] = act[k] ? idx_j[e] : 0;
        at[k] = act[k] ? edge_attr[e] : 0;
    }
    int p[4];
#pragma unroll
    for (int k = 0; k < 4; k++)
        if (act[k]) p[k] = atomicAdd(&cursor[ii[k]], 1);
#pragma unroll
    for (int k = 0; k < 4; k++) {
        if (!act[k]) continue;
        float4 v;
        v.x = d[k];
        v.y = 0.5f * (__cosf(d[k] * PI_OVER_CUT) + 1.0f);
        v.z = __int_as_float(jj[k]);
        v.w = __int_as_float(at[k]);
        edata[p[k]] = v;
        sIarr[p[k]] = ii[k];
    }
}

// ---------------------------------------------------------------------------
// x = ele_emb[z] + res_emb[z_res]
// ---------------------------------------------------------------------------
__global__ void atom_embed(const int* __restrict__ z,
                           const int* __restrict__ z_res,
                           const float* __restrict__ ele_emb,
                           const float* __restrict__ res_emb,
                           float* __restrict__ x, int N) {
    int t = blockIdx.x * blockDim.x + threadIdx.x;
    if (t >= N * NB) return;
    int n = t >> 7, c = t & 127;
    x[t] = ele_emb[z[n] * NB + c] + res_emb[z_res[n] * NB + c];
}

// ---------------------------------------------------------------------------
// xf(bf16, permuted cols) = in(fp32) @ W  via MFMA. First-iteration in2f.
// ---------------------------------------------------------------------------
__global__ __launch_bounds__(256, 4) void node_in2f_mfma(
    const float* __restrict__ x, const short* __restrict__ WT,
    short* __restrict__ xf, int N) {
    __shared__ __align__(16) short XA[64 * HPAD];
    int a0 = blockIdx.x * 64;
    int t = threadIdx.x;
#pragma unroll
    for (int c = 0; c < 4; c++) {
        int chunk = t + c * 256;
        int row = chunk >> 4;
        int col = (chunk & 15) * 8;
        short v[8];
        if (a0 + row < N) {
            const float* src = x + (size_t)(a0 + row) * NB + col;
            float4 f0 = *(const float4*)src;
            float4 f1 = *(const float4*)(src + 4);
            v[0] = f2bs(f0.x); v[1] = f2bs(f0.y); v[2] = f2bs(f0.z); v[3] = f2bs(f0.w);
            v[4] = f2bs(f1.x); v[5] = f2bs(f1.y); v[6] = f2bs(f1.z); v[7] = f2bs(f1.w);
        } else {
#pragma unroll
            for (int j = 0; j < 8; j++) v[j] = 0;
        }
        *(bf16x8*)&XA[row * HPAD + col] = *(bf16x8*)v;
    }
    __syncthreads();

    int wid = t >> 6, lane = t & 63;
    int quad = lane >> 4, col = lane & 15;
    int mrow = wid * 16 + col;

    f32x4 acc[8] = {};
#pragma unroll
    for (int kt = 0; kt < 4; kt++) {
        bf16x8 a = *(bf16x8*)&XA[mrow * HPAD + kt * 32 + quad * 8];
#pragma unroll
        for (int nt = 0; nt < 8; nt++) {
            bf16x8 b = *(const bf16x8*)&WT[(nt * 16 + col) * NB + kt * 32 + quad * 8];
            acc[nt] = __builtin_amdgcn_mfma_f32_16x16x32_bf16(a, b, acc[nt], 0, 0, 0);
        }
    }
#pragma unroll
    for (int nt = 0; nt < 8; nt++) {
        int cst = col * 8 + nt;   // permuted storage col
#pragma unroll
        for (int r = 0; r < 4; r++) {
            int m = wid * 16 + quad * 4 + r;
            if (a0 + m < N) xf[(size_t)(a0 + m) * NB + cst] = f2bs(acc[nt][r]);
        }
    }
}

// ---------------------------------------------------------------------------
// 2-SUBTILE node_fused (r25, confirmed): v = ssp(agg@W1+b1)@W2+b2 ; x += v ;
// xf_next(bf16, permuted) = x @ Wn. 128 threads / 2 waves per 64-atom
// block; per-kt weight fragments loaded once per wave, consumed by both
// subtiles. Staging wave-local -> barrier-free. Re-zeroes its agg rows.
// ---------------------------------------------------------------------------
__global__ __launch_bounds__(128, 1) void node_fused_mfma(
    short* __restrict__ agg,
    const short* __restrict__ W1T, const float* __restrict__ b1,
    const short* __restrict__ W2T, const float* __restrict__ b2,
    const short* __restrict__ WnT,
    float* __restrict__ x, short* __restrict__ xf, int N) {
    __shared__ __align__(16) short XA[64 * HPAD];
    __shared__ __align__(16) short H[64 * HPAD];
    int a0 = blockIdx.x * 64;
    int t = threadIdx.x;                 // [0,128)
    int wid = t >> 6, lane = t & 63;     // 2 waves
    int quad = lane >> 4, col = lane & 15;

    // wave-local staging: wave wid stages its own rows [wid*32, wid*32+32)
#pragma unroll
    for (int c = 0; c < 8; c++) {
        int chunk = lane + c * 64;            // [0,512)
        int row = wid * 32 + (chunk >> 4);    // wave-local row
        int colb = (chunk & 15) * 8;
        bf16x8 v = {0, 0, 0, 0, 0, 0, 0, 0};
        if (a0 + row < N) {
            short* src = agg + (size_t)(a0 + row) * NB + colb;
            v = *(const bf16x8*)src;
            *(bf16x8*)src = (bf16x8){0, 0, 0, 0, 0, 0, 0, 0};  // re-zero
        }
        *(bf16x8*)&XA[row * HPAD + colb] = v;
    }
    asm volatile("s_waitcnt lgkmcnt(0)" ::: "memory");
    __builtin_amdgcn_sched_barrier(0);

    // GEMM1 + ssp -> H (2 subtiles, weights loaded once per kt)
    {
        f32x4 acc[2][8] = {};
#pragma unroll
        for (int kt = 0; kt < 4; kt++) {
            bf16x8 bf[8];
#pragma unroll
            for (int nt = 0; nt < 8; nt++)
                bf[nt] = *(const bf16x8*)&W1T[(nt * 16 + col) * NB + kt * 32 + quad * 8];
#pragma unroll
            for (int s = 0; s < 2; s++) {
                bf16x8 a = *(bf16x8*)&XA[(wid * 32 + s * 16 + col) * HPAD + kt * 32 + quad * 8];
#pragma unroll
                for (int nt = 0; nt < 8; nt++)
                    acc[s][nt] = __builtin_amdgcn_mfma_f32_16x16x32_bf16(a, bf[nt], acc[s][nt], 0, 0, 0);
            }
        }
#pragma unroll
        for (int s = 0; s < 2; s++) {
#pragma unroll
            for (int nt = 0; nt < 8; nt++) {
                int n = nt * 16 + col;
                float bias = b1[n];
#pragma unroll
                for (int r = 0; r < 4; r++) {
                    int m = wid * 32 + s * 16 + quad * 4 + r;
                    H[m * HPAD + n] = f2bs(ssp_f(acc[s][nt][r] + bias));
                }
            }
        }
    }
    asm volatile("s_waitcnt lgkmcnt(0)" ::: "memory");
    __builtin_amdgcn_sched_barrier(0);

    // GEMM2 + residual: x_new -> global fp32 + XA bf16 (reuse)
    {
        f32x4 acc[2][8] = {};
#pragma unroll
        for (int kt = 0; kt < 4; kt++) {
            bf16x8 bf[8];
#pragma unroll
            for (int nt = 0; nt < 8; nt++)
                bf[nt] = *(const bf16x8*)&W2T[(nt * 16 + col) * NB + kt * 32 + quad * 8];
#pragma unroll
            for (int s = 0; s < 2; s++) {
                bf16x8 a = *(bf16x8*)&H[(wid * 32 + s * 16 + col) * HPAD + kt * 32 + quad * 8];
#pragma unroll
                for (int nt = 0; nt < 8; nt++)
                    acc[s][nt] = __builtin_amdgcn_mfma_f32_16x16x32_bf16(a, bf[nt], acc[s][nt], 0, 0, 0);
            }
        }
#pragma unroll
        for (int s = 0; s < 2; s++) {
#pragma unroll
            for (int nt = 0; nt < 8; nt++) {
                int n = nt * 16 + col;
                float bias = b2[n];
#pragma unroll
                for (int r = 0; r < 4; r++) {
                    int m = wid * 32 + s * 16 + quad * 4 + r;
                    float xn = 0.0f;
                    if (a0 + m < N) {
                        size_t o = (size_t)(a0 + m) * NB + n;
                        xn = x[o] + acc[s][nt][r] + bias;
                        x[o] = xn;
                    }
                    XA[m * HPAD + n] = f2bs(xn);
                }
            }
        }
    }
    asm volatile("s_waitcnt lgkmcnt(0)" ::: "memory");
    __builtin_amdgcn_sched_barrier(0);

    // GEMM3: xf = x_new @ Wn  (bf16 out, permuted storage cols)
    {
        f32x4 acc[2][8] = {};
#pragma unroll
        for (int kt = 0; kt < 4; kt++) {
            bf16x8 bf[8];
#pragma unroll
            for (int nt = 0; nt < 8; nt++)
                bf[nt] = *(const bf16x8*)&WnT[(nt * 16 + col) * NB + kt * 32 + quad * 8];
#pragma unroll
            for (int s = 0; s < 2; s++) {
                bf16x8 a = *(bf16x8*)&XA[(wid * 32 + s * 16 + col) * HPAD + kt * 32 + quad * 8];
#pragma unroll
                for (int nt = 0; nt < 8; nt++)
                    acc[s][nt] = __builtin_amdgcn_mfma_f32_16x16x32_bf16(a, bf[nt], acc[s][nt], 0, 0, 0);
            }
        }
#pragma unroll
        for (int s = 0; s < 2; s++) {
#pragma unroll
            for (int nt = 0; nt < 8; nt++) {
                int cst = col * 8 + nt;
#pragma unroll
                for (int r = 0; r < 4; r++) {
                    int m = wid * 32 + s * 16 + quad * 4 + r;
                    if (a0 + m < N) xf[(size_t)(a0 + m) * NB + cst] = f2bs(acc[s][nt][r]);
                }
            }
        }
    }
}

// ---------------------------------------------------------------------------
// Last iteration fused with head: v = ssp(agg@W1+b1)@W2+b2 ; xn = x + v ;
// h = silu(xn/||xn||) ; silu(h@hW1+hb1)@hW2 ; segment-sum by batch.
// ---------------------------------------------------------------------------
__global__ __launch_bounds__(256, 4) void node_out_head_mfma(
    const short* __restrict__ agg,
    const short* __restrict__ W1T, const float* __restrict__ b1,
    const short* __restrict__ W2T, const float* __restrict__ b2,
    const float* __restrict__ x, const int* __restrict__ batch,
    const short* __restrict__ hW1T, const float* __restrict__ hb1,
    const float* __restrict__ hW2,
    float* __restrict__ out, int N) {
    __shared__ __align__(16) short XA[64 * HPAD];
    __shared__ __align__(16) short H[64 * HPAD];
    __shared__ int sbat[64];
    __shared__ float rowval[64];
    int a0 = blockIdx.x * 64;
    int t = threadIdx.x;

    if (t < 64) sbat[t] = (a0 + t < N) ? batch[a0 + t] : -1;
#pragma unroll
    for (int c = 0; c < 4; c++) {
        int chunk = t + c * 256;
        int row = chunk >> 4;
        int col = (chunk & 15) * 8;
        bf16x8 v = {0, 0, 0, 0, 0, 0, 0, 0};
        if (a0 + row < N) v = *(const bf16x8*)&agg[(size_t)(a0 + row) * NB + col];
        *(bf16x8*)&XA[row * HPAD + col] = v;
    }
    __syncthreads();

    int wid = t >> 6, lane = t & 63;
    int quad = lane >> 4, col = lane & 15;
    int mrow = wid * 16 + col;

    // GEMM1 + ssp -> H
    {
        f32x4 acc[8] = {};
#pragma unroll
        for (int kt = 0; kt < 4; kt++) {
            bf16x8 a = *(bf16x8*)&XA[mrow * HPAD + kt * 32 + quad * 8];
#pragma unroll
            for (int nt = 0; nt < 8; nt++) {
                bf16x8 b = *(const bf16x8*)&W1T[(nt * 16 + col) * NB + kt * 32 + quad * 8];
                acc[nt] = __builtin_amdgcn_mfma_f32_16x16x32_bf16(a, b, acc[nt], 0, 0, 0);
            }
        }
#pragma unroll
        for (int nt = 0; nt < 8; nt++) {
            int n = nt * 16 + col;
            float bias = b1[n];
#pragma unroll
            for (int r = 0; r < 4; r++) {
                int m = wid * 16 + quad * 4 + r;
                H[m * HPAD + n] = f2bs(ssp_f(acc[nt][r] + bias));
            }
        }
    }
    __syncthreads();

    // GEMM2 + residual in registers; row sums of squares via 16-lane shuffle
    float xnv[8][4];
    float ssq[4] = {0.f, 0.f, 0.f, 0.f};
    {
        f32x4 acc[8] = {};
#pragma unroll
        for (int kt = 0; kt < 4; kt++) {
            bf16x8 a = *(bf16x8*)&H[mrow * HPAD + kt * 32 + quad * 8];
#pragma unroll
            for (int nt = 0; nt < 8; nt++) {
                bf16x8 b = *(const bf16x8*)&W2T[(nt * 16 + col) * NB + kt * 32 + quad * 8];
                acc[nt] = __builtin_amdgcn_mfma_f32_16x16x32_bf16(a, b, acc[nt], 0, 0, 0);
            }
        }
#pragma unroll
        for (int nt = 0; nt < 8; nt++) {
            int n = nt * 16 + col;
            float bias = b2[n];
#pragma unroll
            for (int r = 0; r < 4; r++) {
                int m = wid * 16 + quad * 4 + r;
                float xn = 0.0f;
                if (a0 + m < N) xn = x[(size_t)(a0 + m) * NB + n] + acc[nt][r] + bias;
                xnv[nt][r] = xn;
                ssq[r] += xn * xn;
            }
        }
    }
#pragma unroll
    for (int r = 0; r < 4; r++) {
#pragma unroll
        for (int m = 1; m < 16; m <<= 1) ssq[r] += __shfl_xor(ssq[r], m);
    }
    float inv[4];
#pragma unroll
    for (int r = 0; r < 4; r++) inv[r] = 1.0f / fmaxf(sqrtf(ssq[r]), 1e-12f);
    __syncthreads();
#pragma unroll
    for (int nt = 0; nt < 8; nt++) {
        int n = nt * 16 + col;
#pragma unroll
        for (int r = 0; r < 4; r++) {
            int m = wid * 16 + quad * 4 + r;
            XA[m * HPAD + n] = f2bs(silu_f(xnv[nt][r] * inv[r]));
        }
    }
    __syncthreads();

    // head GEMM: silu(h@hW1+hb1) dot hW2 per row
    f32x4 acc[8] = {};
#pragma unroll
    for (int kt = 0; kt < 4; kt++) {
        bf16x8 a = *(bf16x8*)&XA[mrow * HPAD + kt * 32 + quad * 8];
#pragma unroll
        for (int nt = 0; nt < 8; nt++) {
            bf16x8 b = *(const bf16x8*)&hW1T[(nt * 16 + col) * NB + kt * 32 + quad * 8];
            acc[nt] = __builtin_amdgcn_mfma_f32_16x16x32_bf16(a, b, acc[nt], 0, 0, 0);
        }
    }
    float partial[4] = {0.f, 0.f, 0.f, 0.f};
#pragma unroll
    for (int nt = 0; nt < 8; nt++) {
        int n = nt * 16 + col;
        float bias = hb1[n];
        float w2 = hW2[n];
#pragma unroll
        for (int r = 0; r < 4; r++) partial[r] += silu_f(acc[nt][r] + bias) * w2;
    }
#pragma unroll
    for (int r = 0; r < 4; r++) {
#pragma unroll
        for (int d = 1; d < 16; d <<= 1) partial[r] += __shfl_xor(partial[r], d);
    }
    if (col == 0) {
#pragma unroll
        for (int r = 0; r < 4; r++) rowval[wid * 16 + quad * 4 + r] = partial[r];
    }
    __syncthreads();

    if (t < 64) {
        int b = sbat[t];
        bool headf = (b >= 0) && (t == 0 || sbat[t - 1] != b);
        if (headf) {
            float s = 0.0f;
            int rr = t;
            while (rr < 64 && sbat[rr] == b) { s += rowval[rr]; rr++; }
            atomicAdd(&out[b], s);
        }
    }
}

// ---------------------------------------------------------------------------
// BARRIER-FREE 2-subtile edge kernel + DIRECT A-FRAGMENT RBF, occupancy
// capped at 3 blk/CU (r28). 128 edges/block, 4 waves, each wave owns 32
// contiguous edges as two M=16 subtiles. f_ij computed in registers in
// MFMA A-layout; weight fragments loaded once per wave. The (256,3) cap
// keeps the concurrent edge window L2-resident (r27's 4 blk/CU blew L2:
// FETCH/WRITE 2.3x, dur +23%).
// ---------------------------------------------------------------------------
__global__ __launch_bounds__(256, 3) void edge_fused_mfma(
    const float4* __restrict__ edata, const int* __restrict__ sIarr,
    const int* __restrict__ rowend, int natoms,
    const float* __restrict__ edge_emb,
    const short* __restrict__ W1T, const float* __restrict__ b1,
    const short* __restrict__ W2T, const float* __restrict__ b2,
    const short* __restrict__ xf, short* __restrict__ agg) {
    __shared__ __align__(16) short H[128 * HPAD];

    int t = threadIdx.x;
    int wid = t >> 6, lane = t & 63;
    int quad = lane >> 4, col = lane & 15;
    int base = blockIdx.x * 128;
    int wbase = base + wid * 32;        // this wave's 32-edge window
    int el32 = lane & 31;               // lane holds record of edge wbase+el32

    // issue record loads immediately (edata/sIarr are E-sized)
    float4 ed = edata[wbase + el32];
    int sIv0 = sIarr[wbase + el32];
    int cnt = rowend[natoms - 1];
    if (base >= cnt) return;

    bool act = (wbase + el32) < cnt;
    float dv  = act ? ed.x : 1e9f;
    float rcv = act ? ed.y : 0.0f;
    int   jjv = act ? __float_as_int(ed.z) : 0;
    int   atv = act ? __float_as_int(ed.w) : 0;
    int   iiv = act ? sIv0 : 0;

    // gathers for both subtiles (permuted xf): one bf16x8 per edge.
    // Latency hides under GEMM1 + ssp + H staging + GEMM2.
    bf16x8 xv[2][4];
    const unsigned short* xg = (const unsigned short*)xf;
#pragma unroll
    for (int s = 0; s < 2; s++) {
#pragma unroll
        for (int r = 0; r < 4; r++) {
            int jj = __shfl(jjv, s * 16 + quad * 4 + r);
            xv[s][r] = *(const bf16x8*)&xg[(size_t)jj * NB + col * 8];
        }
    }

    // GEMM1: hidden = f_ij @ W1 (K=32). A-fragments computed DIRECTLY in
    // registers (f[s*16+col][quad*8+j]); weights loaded once for 2 subtiles.
    {
        bf16x8 b1f[8];
#pragma unroll
        for (int nt = 0; nt < 8; nt++)
            b1f[nt] = *(const bf16x8*)&W1T[(nt * 16 + col) * NR + quad * 8];
#pragma unroll
        for (int s = 0; s < 2; s++) {
            int erow = s * 16 + col;                 // wave-local edge
            float d  = __shfl(dv, erow);
            int   at = __shfl(atv, erow);
            const float* em = edge_emb + at * NR + quad * 8;
            short av[8];
#pragma unroll
            for (int j = 0; j < 8; j++) {
                float off = (float)(quad * 8 + j) * RBF_STEP;
                float dd = d - off;
                av[j] = f2bs(__expf(RBF_COEFF * dd * dd) + em[j]);
            }
            bf16x8 a1 = *(bf16x8*)av;
            f32x4 acc[8];
#pragma unroll
            for (int nt = 0; nt < 8; nt++)
                acc[nt] = __builtin_amdgcn_mfma_f32_16x16x32_bf16(a1, b1f[nt], (f32x4){0.f, 0.f, 0.f, 0.f}, 0, 0, 0);
#pragma unroll
            for (int nt = 0; nt < 8; nt++) {
                int n = nt * 16 + col;
                float bias = b1[n];
#pragma unroll
                for (int r = 0; r < 4; r++) {
                    int m = wid * 32 + s * 16 + quad * 4 + r;
                    H[m * HPAD + n] = f2bs(ssp_f(acc[nt][r] + bias));
                }
            }
        }
    }

    // wave-local LDS fence: H writes -> GEMM2 reads
    asm volatile("s_waitcnt lgkmcnt(0)" ::: "memory");
    __builtin_amdgcn_sched_barrier(0);

    // GEMM2: Wij = hidden @ W2 (K=128); each kt's B-fragments loaded ONCE
    // and consumed by both subtiles (halves W2T traffic).
    f32x4 acc2[2][8] = {};
#pragma unroll
    for (int kt = 0; kt < 4; kt++) {
        bf16x8 b2f[8];
#pragma unroll
        for (int nt = 0; nt < 8; nt++)
            b2f[nt] = *(const bf16x8*)&W2T[(nt * 16 + col) * NB + kt * 32 + quad * 8];
#pragma unroll
        for (int s = 0; s < 2; s++) {
            bf16x8 a = *(bf16x8*)&H[(wid * 32 + s * 16 + col) * HPAD + kt * 32 + quad * 8];
#pragma unroll
            for (int nt = 0; nt < 8; nt++)
                acc2[s][nt] = __builtin_amdgcn_mfma_f32_16x16x32_bf16(a, b2f[nt], acc2[s][nt], 0, 0, 0);
        }
    }

    // epilogue: per subtile, merge equal-atom runs over the quad's 4 edges,
    // flush merged runs with pk atomics (quad-uniform branches).
    float b2v[8];
#pragma unroll
    for (int nt = 0; nt < 8; nt++) b2v[nt] = b2[nt * 16 + col];

#pragma unroll
    for (int s = 0; s < 2; s++) {
        int e0l = s * 16 + quad * 4;
        int cur = __shfl(iiv, e0l);
        float accum[8] = {0.f, 0.f, 0.f, 0.f, 0.f, 0.f, 0.f, 0.f};
#pragma unroll
        for (int r = 0; r < 4; r++) {
            int ii = __shfl(iiv, e0l + r);
            float rc = __shfl(rcv, e0l + r);
            if (ii != cur) {
                flush_pk(agg + (size_t)cur * NB, accum, col);
#pragma unroll
                for (int nt = 0; nt < 8; nt++) accum[nt] = 0.f;
                cur = ii;
            }
#pragma unroll
            for (int nt = 0; nt < 8; nt++) {
                float w = (acc2[s][nt][r] + b2v[nt]) * rc;
                accum[nt] = fmaf(w, bs2f((unsigned short)xv[s][r][nt]), accum[nt]);
            }
        }
        flush_pk(agg + (size_t)cur * NB, accum, col);
    }
}

// ---------------------------------------------------------------------------
extern "C" void kernel_launch(void* const* d_in, const int* in_sizes, int n_in,
                              void* d_out, int out_size, void* d_ws, size_t ws_size,
                              hipStream_t stream) {
    const int*   z        = (const int*)d_in[0];
    const int*   z_res    = (const int*)d_in[1];
    const float* pos      = (const float*)d_in[2];
    const int*   idx_i    = (const int*)d_in[3];
    const int*   idx_j    = (const int*)d_in[4];
    const int*   edge_attr= (const int*)d_in[5];
    const int*   batch    = (const int*)d_in[6];
    const float* ele_emb  = (const float*)d_in[7];
    const float* res_emb  = (const float*)d_in[8];
    const float* edge_emb = (const float*)d_in[9];
    const float* in2f_W   = (const float*)d_in[10];
    const float* filt_W1  = (const float*)d_in[11];
    const float* filt_b1  = (const float*)d_in[12];
    const float* filt_W2  = (const float*)d_in[13];
    const float* filt_b2  = (const float*)d_in[14];
    const float* f2out_W1 = (const float*)d_in[15];
    const float* f2out_b1 = (const float*)d_in[16];
    const float* f2out_W2 = (const float*)d_in[17];
    const float* f2out_b2 = (const float*)d_in[18];
    const float* head_W1  = (const float*)d_in[19];
    const float* head_b1  = (const float*)d_in[20];
    const float* head_W2  = (const float*)d_in[21];

    const int N = in_sizes[0];
    const int E = in_sizes[3];

    char* p = (char*)d_ws;
    size_t off = 0;
    auto carve = [&](size_t bytes) -> void* {
        void* q = p + off;
        off = (off + bytes + 255) & ~(size_t)255;
        return q;
    };
    float*  d_d      = (float*)carve((size_t)E * 4);
    float4* edata    = (float4*)carve((size_t)E * 16);
    int*    sIarr    = (int*)carve((size_t)E * 4);
    int*    hist     = (int*)carve((size_t)N * 4);
    int*    cursor   = (int*)carve((size_t)N * 4);
    int*    partial  = (int*)carve((size_t)SCB * 4);
    float*  x_buf    = (float*)carve((size_t)N * NB * 4);
    short*  xf_buf   = (short*)carve((size_t)N * NB * 2);
    short*  agg      = (short*)carve((size_t)N * NB * 2);
    short*  in2f_WT  = (short*)carve((size_t)6 * NB * NB * 2);
    short*  fW1T     = (short*)carve((size_t)6 * NR * NB * 2);
    short*  fW2T     = (short*)carve((size_t)6 * NB * NB * 2);
    short*  oW1T     = (short*)carve((size_t)6 * NB * NB * 2);
    short*  oW2T     = (short*)carve((size_t)6 * NB * NB * 2);
    short*  hW1T     = (short*)carve((size_t)NB * NB * 2);
    (void)ws_size;

    // weight prep (bf16 transposed)
    {
        int tot = 6 * NB * NB;
        transpose_cvt<<<(tot + 255) / 256, 256, 0, stream>>>(in2f_W, in2f_WT, NB, NB, tot);
        transpose_cvt<<<(tot + 255) / 256, 256, 0, stream>>>(filt_W2, fW2T, NB, NB, tot);
        transpose_cvt<<<(tot + 255) / 256, 256, 0, stream>>>(f2out_W1, oW1T, NB, NB, tot);
        transpose_cvt<<<(tot + 255) / 256, 256, 0, stream>>>(f2out_W2, oW2T, NB, NB, tot);
        int tot1 = 6 * NR * NB;
        transpose_cvt<<<(tot1 + 255) / 256, 256, 0, stream>>>(filt_W1, fW1T, NR, NB, tot1);
        int tot2 = NB * NB;
        transpose_cvt<<<(tot2 + 255) / 256, 256, 0, stream>>>(head_W1, hW1T, NB, NB, tot2);
    }

    // edge prep + idx_i-grouped sort with packed records
    hipMemsetAsync(hist, 0, (size_t)N * 4, stream);
    int nblk_e4 = (E + 1023) / 1024;
    edge_prep4<<<nblk_e4, 256, 0, stream>>>(pos, idx_i, idx_j, d_d, hist, E);
    // multi-block exclusive scan: hist -> cursor (r22)
    scan_reduce<<<SCB, 256, 0, stream>>>(hist, partial, N);
    scan_partials<<<1, SCB, 0, stream>>>(partial);
    scan_expand<<<SCB, 256, 0, stream>>>(hist, partial, cursor, N);
    scatter_sorted4<<<nblk_e4, 256, 0, stream>>>(d_d, idx_i, idx_j, edge_attr,
                                                 cursor, edata, sIarr, E);
    // cursor[a] is now the END of atom a's sorted range; cursor[N-1] = count.

    atom_embed<<<(N * NB + 255) / 256, 256, 0, stream>>>(z, z_res, ele_emb, res_emb, x_buf, N);

    int nblk_atom64 = (N + 63) / 64;
    int nblk_edge = (E + 127) / 128;

    node_in2f_mfma<<<nblk_atom64, 256, 0, stream>>>(x_buf, in2f_WT, xf_buf, N);
    hipMemsetAsync(d_out, 0, (size_t)out_size * sizeof(float), stream);
    hipMemsetAsync(agg, 0, (size_t)N * NB * 2, stream);   // once; node_fused re-zeroes
    for (int i = 0; i < 6; i++) {
        edge_fused_mfma<<<nblk_edge, 256, 0, stream>>>(
            edata, sIarr, cursor, N, edge_emb,
            fW1T + (size_t)i * NR * NB, filt_b1 + (size_t)i * NB,
            fW2T + (size_t)i * NB * NB, filt_b2 + (size_t)i * NB,
            xf_buf, agg);
        if (i < 5) {
            node_fused_mfma<<<nblk_atom64, 128, 0, stream>>>(
                agg, oW1T + (size_t)i * NB * NB, f2out_b1 + (size_t)i * NB,
                oW2T + (size_t)i * NB * NB, f2out_b2 + (size_t)i * NB,
                in2f_WT + (size_t)(i + 1) * NB * NB,
                x_buf, xf_buf, N);
        } else {
            node_out_head_mfma<<<nblk_atom64, 256, 0, stream>>>(
                agg, oW1T + (size_t)i * NB * NB, f2out_b1 + (size_t)i * NB,
                oW2T + (size_t)i * NB * NB, f2out_b2 + (size_t)i * NB,
                x_buf, batch, hW1T, head_b1, head_W2,
                (float*)d_out, N);
        }
    }
}

// Round 14
// 1874.028 us; speedup vs baseline: 1.1780x; 1.0344x over previous
//
#include <hip/hip_runtime.h>
#include <hip/hip_bf16.h>
#include <math.h>

#define NB 128
#define NR 32
#define EPAD 40    // fA row stride in shorts
#define HPAD 136   // H/XA row stride in shorts (272B, 16B-aligned rows)
#define SCB 256    // scan blocks

// r29: REVERT to best-measured configuration (round-10 source, 1875.5us):
// r24 edge (2-subtile, fA-staged RBF, 45KB LDS -> 3 blk/CU L2-resident),
// r25 nodes (2-subtile barrier-free), r22 multi-block scan.
// r28 post-mortem: __launch_bounds__ 2nd arg is a MINIMUM waves/EU, not an
// occupancy cap -> 34.8KB LDS still ran 4 blk/CU part-time (L2 traffic
// elevated); and direct-RBF's shfl+repack chain sits on the critical path
// before GEMM1, while r24's fA staging is latency-hidden ds_read_b128.
// Confirmed levers: r22 fast scan (-150), r24 edge 2-subtile (-284),
// r25 node 2-subtile (-48). Falsified: r5/r6/r7/r10/r12/r14/r16/r17/r18/
// r20/r21/r26 (occupancy collapse)/r27+r28 (direct-RBF, L2 window growth).
// Edge profile at this config: HBM 19%, VALU 43%, Mfma 6.5% -- no
// saturated resource; occupancy<->L2-residency optimum is this config.

static constexpr float CUTOFF_F    = 10.0f;
static constexpr float RBF_STEP    = 10.0f / 31.0f;
static constexpr float RBF_COEFF   = -4.805f;           // -0.5/(10/31)^2
static constexpr float LOG2_F      = 0.69314718055994531f;
static constexpr float PI_OVER_CUT = 0.314159265358979f;

typedef __attribute__((ext_vector_type(8))) short bf16x8;
typedef __attribute__((ext_vector_type(2))) short bf16x2;
typedef __attribute__((ext_vector_type(4))) float f32x4;

__device__ __forceinline__ short f2bs(float x) {
    __hip_bfloat16 h = __float2bfloat16(x);   // RNE
    return *reinterpret_cast<short*>(&h);
}
__device__ __forceinline__ float bs2f(unsigned short u) {
    unsigned int v = ((unsigned int)u) << 16;
    return __uint_as_float(v);
}
__device__ __forceinline__ float ssp_f(float v) {
    return fmaxf(v, 0.0f) + __logf(1.0f + __expf(-fabsf(v))) - LOG2_F;
}
__device__ __forceinline__ float silu_f(float v) {
    return v / (1.0f + __expf(-v));
}

// packed bf16 atomic add (2 features per op)
__device__ __forceinline__ void atomic_pk_add_bf16(short* addr, float lo, float hi) {
#if __has_builtin(__builtin_amdgcn_global_atomic_fadd_v2bf16)
    typedef bf16x2 __attribute__((address_space(1))) *gptr;
    bf16x2 v;
    v[0] = f2bs(lo);
    v[1] = f2bs(hi);
    __builtin_amdgcn_global_atomic_fadd_v2bf16((gptr)(unsigned long long)addr, v);
#else
    unsigned int* w = (unsigned int*)addr;
    unsigned int old = *w, assumed;
    do {
        assumed = old;
        float fl = bs2f((unsigned short)(assumed & 0xffff)) + lo;
        float fh = bs2f((unsigned short)(assumed >> 16)) + hi;
        unsigned int nv = ((unsigned int)(unsigned short)f2bs(fh) << 16) |
                          (unsigned short)f2bs(fl);
        old = atomicCAS(w, assumed, nv);
    } while (old != assumed);
#endif
}

// flush one merged run: 8 accumulated features/lane -> 4 pk atomics/lane.
// Run boundaries are quad-uniform so the lane^1 shuffles pair active lanes.
__device__ __forceinline__ void flush_pk(short* aggrow, const float* accum, int col) {
    bool even = ((col & 1) == 0);
#pragma unroll
    for (int q = 0; q < 4; q++) {
        float a = accum[2 * q], b = accum[2 * q + 1];
        float pa = __shfl_xor(a, 1);   // feature (2q)*16 + (col^1)
        float pb = __shfl_xor(b, 1);
        int nbase = even ? (2 * q) * 16 + col : (2 * q + 1) * 16 + (col - 1);
        float lo = even ? a : pb;
        float hi = even ? pa : b;
        atomic_pk_add_bf16(aggrow + nbase, lo, hi);
    }
}

// ---------------------------------------------------------------------------
// Weight prep: dst[b][c][r] = bf16(src[b][r][c])
// ---------------------------------------------------------------------------
__global__ void transpose_cvt(const float* __restrict__ src, short* __restrict__ dst,
                              int R, int C, int total) {
    int t = blockIdx.x * blockDim.x + threadIdx.x;
    if (t >= total) return;
    int rc = R * C;
    int b = t / rc;
    int rem = t - b * rc;
    int c = rem / R;
    int r = rem - c * R;
    dst[t] = f2bs(src[(size_t)b * rc + (size_t)r * C + c]);
}

// ---------------------------------------------------------------------------
// Edge prep: distances + per-atom histogram. 4 edges/thread for MLP.
// ---------------------------------------------------------------------------
__global__ void edge_prep4(const float* __restrict__ pos,
                           const int* __restrict__ idx_i,
                           const int* __restrict__ idx_j,
                           float* __restrict__ d_ij,
                           int* __restrict__ hist,
                           int E) {
    int b0 = blockIdx.x * 1024 + threadIdx.x;
    int ia[4], ib[4];
    bool val[4];
#pragma unroll
    for (int k = 0; k < 4; k++) {
        int e = b0 + k * 256;
        val[k] = (e < E);
        ia[k] = val[k] ? idx_i[e] : 0;
        ib[k] = val[k] ? idx_j[e] : 0;
    }
    float ax[4], ay[4], az[4], bx[4], by[4], bz[4];
#pragma unroll
    for (int k = 0; k < 4; k++) {
        const float* pa = pos + ia[k] * 3;
        ax[k] = pa[0]; ay[k] = pa[1]; az[k] = pa[2];
    }
#pragma unroll
    for (int k = 0; k < 4; k++) {
        const float* pb = pos + ib[k] * 3;
        bx[k] = pb[0]; by[k] = pb[1]; bz[k] = pb[2];
    }
#pragma unroll
    for (int k = 0; k < 4; k++) {
        if (!val[k]) continue;
        float dx = ax[k] - bx[k], dy = ay[k] - by[k], dz = az[k] - bz[k];
        float d = sqrtf(dx * dx + dy * dy + dz * dz);
        d_ij[b0 + k * 256] = d;
        if (d < CUTOFF_F) atomicAdd(&hist[ia[k]], 1);
    }
}

// ---------------------------------------------------------------------------
// Multi-block exclusive scan of hist[N] -> cursor[N]  (r22, ~12us).
// ---------------------------------------------------------------------------
__global__ __launch_bounds__(256) void scan_reduce(const int* __restrict__ hist,
                                                   int* __restrict__ partial, int N) {
    __shared__ int red[256];
    int b = blockIdx.x;
    int chunk = (N + SCB - 1) / SCB;
    int lo = b * chunk;
    int hi = min(lo + chunk, N);
    int s = 0;
    for (int i = lo + threadIdx.x; i < hi; i += 256) s += hist[i];
    red[threadIdx.x] = s;
    __syncthreads();
    for (int d = 128; d > 0; d >>= 1) {
        if (threadIdx.x < d) red[threadIdx.x] += red[threadIdx.x + d];
        __syncthreads();
    }
    if (threadIdx.x == 0) partial[b] = red[0];
}

__global__ __launch_bounds__(256) void scan_partials(int* __restrict__ partial) {
    __shared__ int sm[SCB];
    int t = threadIdx.x;
    sm[t] = partial[t];
    __syncthreads();
    for (int d = 1; d < SCB; d <<= 1) {
        int v = (t >= d) ? sm[t - d] : 0;
        __syncthreads();
        sm[t] += v;
        __syncthreads();
    }
    partial[t] = (t == 0) ? 0 : sm[t - 1];   // exclusive
}

__global__ __launch_bounds__(256) void scan_expand(const int* __restrict__ hist,
                                                   const int* __restrict__ partial,
                                                   int* __restrict__ cursor, int N) {
    __shared__ int tsum[256];
    int b = blockIdx.x;
    int chunk = (N + SCB - 1) / SCB;
    int lo = b * chunk;
    int hi = min(lo + chunk, N);
    int sub = (chunk + 255) / 256;
    int tlo = lo + threadIdx.x * sub;
    int thi = min(tlo + sub, hi);
    int s = 0;
    for (int i = tlo; i < thi; i++) s += hist[i];
    int t = threadIdx.x;
    tsum[t] = s;
    __syncthreads();
    for (int d = 1; d < 256; d <<= 1) {
        int v = (t >= d) ? tsum[t - d] : 0;
        __syncthreads();
        tsum[t] += v;
        __syncthreads();
    }
    int run = partial[b] + ((t == 0) ? 0 : tsum[t - 1]);
    for (int i = tlo; i < thi; i++) {
        cursor[i] = run;
        run += hist[i];
    }
}

// ---------------------------------------------------------------------------
// Scatter active edges into idx_i-grouped order. 4 edges/thread for MLP.
// Computes rcut for active edges only. After: cursor[a] == end of range.
// ---------------------------------------------------------------------------
__global__ void scatter_sorted4(const float* __restrict__ d_ij,
                                const int* __restrict__ idx_i,
                                const int* __restrict__ idx_j,
                                const int* __restrict__ edge_attr,
                                int* __restrict__ cursor,
                                float4* __restrict__ edata,
                                int* __restrict__ sIarr, int E) {
    int b0 = blockIdx.x * 1024 + threadIdx.x;
    float d[4]; int ii[4], jj[4], at[4]; bool act[4];
#pragma unroll
    for (int k = 0; k < 4; k++) {
        int e = b0 + k * 256;
        bool v = (e < E);
        d[k] = v ? d_ij[e] : 1e9f;
        act[k] = (d[k] < CUTOFF_F);
        ii[k] = act[k] ? idx_i[e] : 0;
        jj[k] = act[k] ? idx_j[e] : 0;
        at[k] = act[k] ? edge_attr[e] : 0;
    }
    int p[4];
#pragma unroll
    for (int k = 0; k < 4; k++)
        if (act[k]) p[k] = atomicAdd(&cursor[ii[k]], 1);
#pragma unroll
    for (int k = 0; k < 4; k++) {
        if (!act[k]) continue;
        float4 v;
        v.x = d[k];
        v.y = 0.5f * (__cosf(d[k] * PI_OVER_CUT) + 1.0f);
        v.z = __int_as_float(jj[k]);
        v.w = __int_as_float(at[k]);
        edata[p[k]] = v;
        sIarr[p[k]] = ii[k];
    }
}

// ---------------------------------------------------------------------------
// x = ele_emb[z] + res_emb[z_res]
// ---------------------------------------------------------------------------
__global__ void atom_embed(const int* __restrict__ z,
                           const int* __restrict__ z_res,
                           const float* __restrict__ ele_emb,
                           const float* __restrict__ res_emb,
                           float* __restrict__ x, int N) {
    int t = blockIdx.x * blockDim.x + threadIdx.x;
    if (t >= N * NB) return;
    int n = t >> 7, c = t & 127;
    x[t] = ele_emb[z[n] * NB + c] + res_emb[z_res[n] * NB + c];
}

// ---------------------------------------------------------------------------
// xf(bf16, permuted cols) = in(fp32) @ W  via MFMA. First-iteration in2f.
// ---------------------------------------------------------------------------
__global__ __launch_bounds__(256, 4) void node_in2f_mfma(
    const float* __restrict__ x, const short* __restrict__ WT,
    short* __restrict__ xf, int N) {
    __shared__ __align__(16) short XA[64 * HPAD];
    int a0 = blockIdx.x * 64;
    int t = threadIdx.x;
#pragma unroll
    for (int c = 0; c < 4; c++) {
        int chunk = t + c * 256;
        int row = chunk >> 4;
        int col = (chunk & 15) * 8;
        short v[8];
        if (a0 + row < N) {
            const float* src = x + (size_t)(a0 + row) * NB + col;
            float4 f0 = *(const float4*)src;
            float4 f1 = *(const float4*)(src + 4);
            v[0] = f2bs(f0.x); v[1] = f2bs(f0.y); v[2] = f2bs(f0.z); v[3] = f2bs(f0.w);
            v[4] = f2bs(f1.x); v[5] = f2bs(f1.y); v[6] = f2bs(f1.z); v[7] = f2bs(f1.w);
        } else {
#pragma unroll
            for (int j = 0; j < 8; j++) v[j] = 0;
        }
        *(bf16x8*)&XA[row * HPAD + col] = *(bf16x8*)v;
    }
    __syncthreads();

    int wid = t >> 6, lane = t & 63;
    int quad = lane >> 4, col = lane & 15;
    int mrow = wid * 16 + col;

    f32x4 acc[8] = {};
#pragma unroll
    for (int kt = 0; kt < 4; kt++) {
        bf16x8 a = *(bf16x8*)&XA[mrow * HPAD + kt * 32 + quad * 8];
#pragma unroll
        for (int nt = 0; nt < 8; nt++) {
            bf16x8 b = *(const bf16x8*)&WT[(nt * 16 + col) * NB + kt * 32 + quad * 8];
            acc[nt] = __builtin_amdgcn_mfma_f32_16x16x32_bf16(a, b, acc[nt], 0, 0, 0);
        }
    }
#pragma unroll
    for (int nt = 0; nt < 8; nt++) {
        int cst = col * 8 + nt;   // permuted storage col
#pragma unroll
        for (int r = 0; r < 4; r++) {
            int m = wid * 16 + quad * 4 + r;
            if (a0 + m < N) xf[(size_t)(a0 + m) * NB + cst] = f2bs(acc[nt][r]);
        }
    }
}

// ---------------------------------------------------------------------------
// 2-SUBTILE node_fused (r25): v = ssp(agg@W1+b1)@W2+b2 ; x += v ;
// xf_next(bf16, permuted) = x @ Wn. 128 threads / 2 waves per 64-atom
// block; wave owns 32 atoms as two M=16 subtiles; per-kt weight fragments
// loaded once per wave, consumed by both subtiles. Staging wave-local ->
// barrier-free (lgkmcnt fences). Re-zeroes its agg rows.
// ---------------------------------------------------------------------------
__global__ __launch_bounds__(128, 1) void node_fused_mfma(
    short* __restrict__ agg,
    const short* __restrict__ W1T, const float* __restrict__ b1,
    const short* __restrict__ W2T, const float* __restrict__ b2,
    const short* __restrict__ WnT,
    float* __restrict__ x, short* __restrict__ xf, int N) {
    __shared__ __align__(16) short XA[64 * HPAD];
    __shared__ __align__(16) short H[64 * HPAD];
    int a0 = blockIdx.x * 64;
    int t = threadIdx.x;                 // [0,128)
    int wid = t >> 6, lane = t & 63;     // 2 waves
    int quad = lane >> 4, col = lane & 15;

    // wave-local staging: wave wid stages its own rows [wid*32, wid*32+32)
#pragma unroll
    for (int c = 0; c < 8; c++) {
        int chunk = lane + c * 64;            // [0,512)
        int row = wid * 32 + (chunk >> 4);    // wave-local row
        int colb = (chunk & 15) * 8;
        bf16x8 v = {0, 0, 0, 0, 0, 0, 0, 0};
        if (a0 + row < N) {
            short* src = agg + (size_t)(a0 + row) * NB + colb;
            v = *(const bf16x8*)src;
            *(bf16x8*)src = (bf16x8){0, 0, 0, 0, 0, 0, 0, 0};  // re-zero
        }
        *(bf16x8*)&XA[row * HPAD + colb] = v;
    }
    asm volatile("s_waitcnt lgkmcnt(0)" ::: "memory");
    __builtin_amdgcn_sched_barrier(0);

    // GEMM1 + ssp -> H (2 subtiles, weights loaded once per kt)
    {
        f32x4 acc[2][8] = {};
#pragma unroll
        for (int kt = 0; kt < 4; kt++) {
            bf16x8 bf[8];
#pragma unroll
            for (int nt = 0; nt < 8; nt++)
                bf[nt] = *(const bf16x8*)&W1T[(nt * 16 + col) * NB + kt * 32 + quad * 8];
#pragma unroll
            for (int s = 0; s < 2; s++) {
                bf16x8 a = *(bf16x8*)&XA[(wid * 32 + s * 16 + col) * HPAD + kt * 32 + quad * 8];
#pragma unroll
                for (int nt = 0; nt < 8; nt++)
                    acc[s][nt] = __builtin_amdgcn_mfma_f32_16x16x32_bf16(a, bf[nt], acc[s][nt], 0, 0, 0);
            }
        }
#pragma unroll
        for (int s = 0; s < 2; s++) {
#pragma unroll
            for (int nt = 0; nt < 8; nt++) {
                int n = nt * 16 + col;
                float bias = b1[n];
#pragma unroll
                for (int r = 0; r < 4; r++) {
                    int m = wid * 32 + s * 16 + quad * 4 + r;
                    H[m * HPAD + n] = f2bs(ssp_f(acc[s][nt][r] + bias));
                }
            }
        }
    }
    asm volatile("s_waitcnt lgkmcnt(0)" ::: "memory");
    __builtin_amdgcn_sched_barrier(0);

    // GEMM2 + residual: x_new -> global fp32 + XA bf16 (reuse)
    {
        f32x4 acc[2][8] = {};
#pragma unroll
        for (int kt = 0; kt < 4; kt++) {
            bf16x8 bf[8];
#pragma unroll
            for (int nt = 0; nt < 8; nt++)
                bf[nt] = *(const bf16x8*)&W2T[(nt * 16 + col) * NB + kt * 32 + quad * 8];
#pragma unroll
            for (int s = 0; s < 2; s++) {
                bf16x8 a = *(bf16x8*)&H[(wid * 32 + s * 16 + col) * HPAD + kt * 32 + quad * 8];
#pragma unroll
                for (int nt = 0; nt < 8; nt++)
                    acc[s][nt] = __builtin_amdgcn_mfma_f32_16x16x32_bf16(a, bf[nt], acc[s][nt], 0, 0, 0);
            }
        }
#pragma unroll
        for (int s = 0; s < 2; s++) {
#pragma unroll
            for (int nt = 0; nt < 8; nt++) {
                int n = nt * 16 + col;
                float bias = b2[n];
#pragma unroll
                for (int r = 0; r < 4; r++) {
                    int m = wid * 32 + s * 16 + quad * 4 + r;
                    float xn = 0.0f;
                    if (a0 + m < N) {
                        size_t o = (size_t)(a0 + m) * NB + n;
                        xn = x[o] + acc[s][nt][r] + bias;
                        x[o] = xn;
                    }
                    XA[m * HPAD + n] = f2bs(xn);
                }
            }
        }
    }
    asm volatile("s_waitcnt lgkmcnt(0)" ::: "memory");
    __builtin_amdgcn_sched_barrier(0);

    // GEMM3: xf = x_new @ Wn  (bf16 out, permuted storage cols)
    {
        f32x4 acc[2][8] = {};
#pragma unroll
        for (int kt = 0; kt < 4; kt++) {
            bf16x8 bf[8];
#pragma unroll
            for (int nt = 0; nt < 8; nt++)
                bf[nt] = *(const bf16x8*)&WnT[(nt * 16 + col) * NB + kt * 32 + quad * 8];
#pragma unroll
            for (int s = 0; s < 2; s++) {
                bf16x8 a = *(bf16x8*)&XA[(wid * 32 + s * 16 + col) * HPAD + kt * 32 + quad * 8];
#pragma unroll
                for (int nt = 0; nt < 8; nt++)
                    acc[s][nt] = __builtin_amdgcn_mfma_f32_16x16x32_bf16(a, bf[nt], acc[s][nt], 0, 0, 0);
            }
        }
#pragma unroll
        for (int s = 0; s < 2; s++) {
#pragma unroll
            for (int nt = 0; nt < 8; nt++) {
                int cst = col * 8 + nt;
#pragma unroll
                for (int r = 0; r < 4; r++) {
                    int m = wid * 32 + s * 16 + quad * 4 + r;
                    if (a0 + m < N) xf[(size_t)(a0 + m) * NB + cst] = f2bs(acc[s][nt][r]);
                }
            }
        }
    }
}

// ---------------------------------------------------------------------------
// Last iteration fused with head: v = ssp(agg@W1+b1)@W2+b2 ; xn = x + v ;
// h = silu(xn/||xn||) ; silu(h@hW1+hb1)@hW2 ; segment-sum by batch.
// ---------------------------------------------------------------------------
__global__ __launch_bounds__(256, 4) void node_out_head_mfma(
    const short* __restrict__ agg,
    const short* __restrict__ W1T, const float* __restrict__ b1,
    const short* __restrict__ W2T, const float* __restrict__ b2,
    const float* __restrict__ x, const int* __restrict__ batch,
    const short* __restrict__ hW1T, const float* __restrict__ hb1,
    const float* __restrict__ hW2,
    float* __restrict__ out, int N) {
    __shared__ __align__(16) short XA[64 * HPAD];
    __shared__ __align__(16) short H[64 * HPAD];
    __shared__ int sbat[64];
    __shared__ float rowval[64];
    int a0 = blockIdx.x * 64;
    int t = threadIdx.x;

    if (t < 64) sbat[t] = (a0 + t < N) ? batch[a0 + t] : -1;
#pragma unroll
    for (int c = 0; c < 4; c++) {
        int chunk = t + c * 256;
        int row = chunk >> 4;
        int col = (chunk & 15) * 8;
        bf16x8 v = {0, 0, 0, 0, 0, 0, 0, 0};
        if (a0 + row < N) v = *(const bf16x8*)&agg[(size_t)(a0 + row) * NB + col];
        *(bf16x8*)&XA[row * HPAD + col] = v;
    }
    __syncthreads();

    int wid = t >> 6, lane = t & 63;
    int quad = lane >> 4, col = lane & 15;
    int mrow = wid * 16 + col;

    // GEMM1 + ssp -> H
    {
        f32x4 acc[8] = {};
#pragma unroll
        for (int kt = 0; kt < 4; kt++) {
            bf16x8 a = *(bf16x8*)&XA[mrow * HPAD + kt * 32 + quad * 8];
#pragma unroll
            for (int nt = 0; nt < 8; nt++) {
                bf16x8 b = *(const bf16x8*)&W1T[(nt * 16 + col) * NB + kt * 32 + quad * 8];
                acc[nt] = __builtin_amdgcn_mfma_f32_16x16x32_bf16(a, b, acc[nt], 0, 0, 0);
            }
        }
#pragma unroll
        for (int nt = 0; nt < 8; nt++) {
            int n = nt * 16 + col;
            float bias = b1[n];
#pragma unroll
            for (int r = 0; r < 4; r++) {
                int m = wid * 16 + quad * 4 + r;
                H[m * HPAD + n] = f2bs(ssp_f(acc[nt][r] + bias));
            }
        }
    }
    __syncthreads();

    // GEMM2 + residual in registers; row sums of squares via 16-lane shuffle
    float xnv[8][4];
    float ssq[4] = {0.f, 0.f, 0.f, 0.f};
    {
        f32x4 acc[8] = {};
#pragma unroll
        for (int kt = 0; kt < 4; kt++) {
            bf16x8 a = *(bf16x8*)&H[mrow * HPAD + kt * 32 + quad * 8];
#pragma unroll
            for (int nt = 0; nt < 8; nt++) {
                bf16x8 b = *(const bf16x8*)&W2T[(nt * 16 + col) * NB + kt * 32 + quad * 8];
                acc[nt] = __builtin_amdgcn_mfma_f32_16x16x32_bf16(a, b, acc[nt], 0, 0, 0);
            }
        }
#pragma unroll
        for (int nt = 0; nt < 8; nt++) {
            int n = nt * 16 + col;
            float bias = b2[n];
#pragma unroll
            for (int r = 0; r < 4; r++) {
                int m = wid * 16 + quad * 4 + r;
                float xn = 0.0f;
                if (a0 + m < N) xn = x[(size_t)(a0 + m) * NB + n] + acc[nt][r] + bias;
                xnv[nt][r] = xn;
                ssq[r] += xn * xn;
            }
        }
    }
#pragma unroll
    for (int r = 0; r < 4; r++) {
#pragma unroll
        for (int m = 1; m < 16; m <<= 1) ssq[r] += __shfl_xor(ssq[r], m);
    }
    float inv[4];
#pragma unroll
    for (int r = 0; r < 4; r++) inv[r] = 1.0f / fmaxf(sqrtf(ssq[r]), 1e-12f);
    __syncthreads();
#pragma unroll
    for (int nt = 0; nt < 8; nt++) {
        int n = nt * 16 + col;
#pragma unroll
        for (int r = 0; r < 4; r++) {
            int m = wid * 16 + quad * 4 + r;
            XA[m * HPAD + n] = f2bs(silu_f(xnv[nt][r] * inv[r]));
        }
    }
    __syncthreads();

    // head GEMM: silu(h@hW1+hb1) dot hW2 per row
    f32x4 acc[8] = {};
#pragma unroll
    for (int kt = 0; kt < 4; kt++) {
        bf16x8 a = *(bf16x8*)&XA[mrow * HPAD + kt * 32 + quad * 8];
#pragma unroll
        for (int nt = 0; nt < 8; nt++) {
            bf16x8 b = *(const bf16x8*)&hW1T[(nt * 16 + col) * NB + kt * 32 + quad * 8];
            acc[nt] = __builtin_amdgcn_mfma_f32_16x16x32_bf16(a, b, acc[nt], 0, 0, 0);
        }
    }
    float partial[4] = {0.f, 0.f, 0.f, 0.f};
#pragma unroll
    for (int nt = 0; nt < 8; nt++) {
        int n = nt * 16 + col;
        float bias = hb1[n];
        float w2 = hW2[n];
#pragma unroll
        for (int r = 0; r < 4; r++) partial[r] += silu_f(acc[nt][r] + bias) * w2;
    }
#pragma unroll
    for (int r = 0; r < 4; r++) {
#pragma unroll
        for (int d = 1; d < 16; d <<= 1) partial[r] += __shfl_xor(partial[r], d);
    }
    if (col == 0) {
#pragma unroll
        for (int r = 0; r < 4; r++) rowval[wid * 16 + quad * 4 + r] = partial[r];
    }
    __syncthreads();

    if (t < 64) {
        int b = sbat[t];
        bool headf = (b >= 0) && (t == 0 || sbat[t - 1] != b);
        if (headf) {
            float s = 0.0f;
            int rr = t;
            while (rr < 64 && sbat[rr] == b) { s += rowval[rr]; rr++; }
            atomicAdd(&out[b], s);
        }
    }
}

// ---------------------------------------------------------------------------
// BARRIER-FREE 2-subtile edge kernel (r24, confirmed 176us). 128 edges/
// block, 4 waves, each wave owns 32 contiguous edges as two M=16 subtiles.
// Weight B-fragments loaded once per wave, reused by both subtiles.
// ---------------------------------------------------------------------------
__global__ __launch_bounds__(256, 3) void edge_fused_mfma(
    const float4* __restrict__ edata, const int* __restrict__ sIarr,
    const int* __restrict__ rowend, int natoms,
    const float* __restrict__ edge_emb,
    const short* __restrict__ W1T, const float* __restrict__ b1,
    const short* __restrict__ W2T, const float* __restrict__ b2,
    const short* __restrict__ xf, short* __restrict__ agg) {
    __shared__ __align__(16) short fA[128 * EPAD];
    __shared__ __align__(16) short H[128 * HPAD];

    int t = threadIdx.x;
    int wid = t >> 6, lane = t & 63;
    int quad = lane >> 4, col = lane & 15;
    int base = blockIdx.x * 128;
    int wbase = base + wid * 32;        // this wave's 32-edge window
    int el32 = lane & 31;               // lane holds record of edge wbase+el32

    // issue record loads immediately (edata/sIarr are E-sized)
    float4 ed = edata[wbase + el32];
    int sIv0 = sIarr[wbase + el32];
    int cnt = rowend[natoms - 1];
    if (base >= cnt) return;

    bool act = (wbase + el32) < cnt;
    float dv  = act ? ed.x : 1e9f;
    float rcv = act ? ed.y : 0.0f;
    int   jjv = act ? __float_as_int(ed.z) : 0;
    int   atv = act ? __float_as_int(ed.w) : 0;
    int   iiv = act ? sIv0 : 0;

    // stage A: f_ij tile (RBF + edge_emb), bf16. Lane covers row lane>>1
    // of the wave's 32 rows, 16 shorts at (lane&1)*16.
    {
        int elA = lane >> 1;                 // [0,32)
        int r0 = (lane & 1) * 16;
        float d  = __shfl(dv, elA);
        int   at = __shfl(atv, elA);
        const float* em = edge_emb + at * NR + r0;
        short v[16];
#pragma unroll
        for (int j = 0; j < 16; j++) {
            float off = (float)(r0 + j) * RBF_STEP;
            float dd = d - off;
            v[j] = f2bs(__expf(RBF_COEFF * dd * dd) + em[j]);
        }
        short* dst = &fA[(wid * 32 + elA) * EPAD + r0];
        *(bf16x8*)dst = *(bf16x8*)v;
        *(bf16x8*)(dst + 8) = *(bf16x8*)(v + 8);
    }

    // gathers for both subtiles (permuted xf): one bf16x8 per edge.
    // Latency hides under GEMM1 + ssp + H staging + GEMM2.
    bf16x8 xv[2][4];
    const unsigned short* xg = (const unsigned short*)xf;
#pragma unroll
    for (int s = 0; s < 2; s++) {
#pragma unroll
        for (int r = 0; r < 4; r++) {
            int jj = __shfl(jjv, s * 16 + quad * 4 + r);
            xv[s][r] = *(const bf16x8*)&xg[(size_t)jj * NB + col * 8];
        }
    }

    // wave-local LDS fence: fA writes -> GEMM1 reads
    asm volatile("s_waitcnt lgkmcnt(0)" ::: "memory");
    __builtin_amdgcn_sched_barrier(0);

    // GEMM1: hidden = f_ij @ W1 (K=32), weights loaded ONCE for 2 subtiles
    {
        bf16x8 b1f[8];
#pragma unroll
        for (int nt = 0; nt < 8; nt++)
            b1f[nt] = *(const bf16x8*)&W1T[(nt * 16 + col) * NR + quad * 8];
#pragma unroll
        for (int s = 0; s < 2; s++) {
            bf16x8 a1 = *(bf16x8*)&fA[(wid * 32 + s * 16 + col) * EPAD + quad * 8];
            f32x4 acc[8];
#pragma unroll
            for (int nt = 0; nt < 8; nt++)
                acc[nt] = __builtin_amdgcn_mfma_f32_16x16x32_bf16(a1, b1f[nt], (f32x4){0.f, 0.f, 0.f, 0.f}, 0, 0, 0);
#pragma unroll
            for (int nt = 0; nt < 8; nt++) {
                int n = nt * 16 + col;
                float bias = b1[n];
#pragma unroll
                for (int r = 0; r < 4; r++) {
                    int m = wid * 32 + s * 16 + quad * 4 + r;
                    H[m * HPAD + n] = f2bs(ssp_f(acc[nt][r] + bias));
                }
            }
        }
    }

    // wave-local LDS fence: H writes -> GEMM2 reads
    asm volatile("s_waitcnt lgkmcnt(0)" ::: "memory");
    __builtin_amdgcn_sched_barrier(0);

    // GEMM2: Wij = hidden @ W2 (K=128); each kt's B-fragments loaded ONCE
    // and consumed by both subtiles (halves W2T traffic).
    f32x4 acc2[2][8] = {};
#pragma unroll
    for (int kt = 0; kt < 4; kt++) {
        bf16x8 b2f[8];
#pragma unroll
        for (int nt = 0; nt < 8; nt++)
            b2f[nt] = *(const bf16x8*)&W2T[(nt * 16 + col) * NB + kt * 32 + quad * 8];
#pragma unroll
        for (int s = 0; s < 2; s++) {
            bf16x8 a = *(bf16x8*)&H[(wid * 32 + s * 16 + col) * HPAD + kt * 32 + quad * 8];
#pragma unroll
            for (int nt = 0; nt < 8; nt++)
                acc2[s][nt] = __builtin_amdgcn_mfma_f32_16x16x32_bf16(a, b2f[nt], acc2[s][nt], 0, 0, 0);
        }
    }

    // epilogue: per subtile, merge equal-atom runs over the quad's 4 edges,
    // flush merged runs with pk atomics (quad-uniform branches).
    float b2v[8];
#pragma unroll
    for (int nt = 0; nt < 8; nt++) b2v[nt] = b2[nt * 16 + col];

#pragma unroll
    for (int s = 0; s < 2; s++) {
        int e0l = s * 16 + quad * 4;
        int cur = __shfl(iiv, e0l);
        float accum[8] = {0.f, 0.f, 0.f, 0.f, 0.f, 0.f, 0.f, 0.f};
#pragma unroll
        for (int r = 0; r < 4; r++) {
            int ii = __shfl(iiv, e0l + r);
            float rc = __shfl(rcv, e0l + r);
            if (ii != cur) {
                flush_pk(agg + (size_t)cur * NB, accum, col);
#pragma unroll
                for (int nt = 0; nt < 8; nt++) accum[nt] = 0.f;
                cur = ii;
            }
#pragma unroll
            for (int nt = 0; nt < 8; nt++) {
                float w = (acc2[s][nt][r] + b2v[nt]) * rc;
                accum[nt] = fmaf(w, bs2f((unsigned short)xv[s][r][nt]), accum[nt]);
            }
        }
        flush_pk(agg + (size_t)cur * NB, accum, col);
    }
}

// ---------------------------------------------------------------------------
extern "C" void kernel_launch(void* const* d_in, const int* in_sizes, int n_in,
                              void* d_out, int out_size, void* d_ws, size_t ws_size,
                              hipStream_t stream) {
    const int*   z        = (const int*)d_in[0];
    const int*   z_res    = (const int*)d_in[1];
    const float* pos      = (const float*)d_in[2];
    const int*   idx_i    = (const int*)d_in[3];
    const int*   idx_j    = (const int*)d_in[4];
    const int*   edge_attr= (const int*)d_in[5];
    const int*   batch    = (const int*)d_in[6];
    const float* ele_emb  = (const float*)d_in[7];
    const float* res_emb  = (const float*)d_in[8];
    const float* edge_emb = (const float*)d_in[9];
    const float* in2f_W   = (const float*)d_in[10];
    const float* filt_W1  = (const float*)d_in[11];
    const float* filt_b1  = (const float*)d_in[12];
    const float* filt_W2  = (const float*)d_in[13];
    const float* filt_b2  = (const float*)d_in[14];
    const float* f2out_W1 = (const float*)d_in[15];
    const float* f2out_b1 = (const float*)d_in[16];
    const float* f2out_W2 = (const float*)d_in[17];
    const float* f2out_b2 = (const float*)d_in[18];
    const float* head_W1  = (const float*)d_in[19];
    const float* head_b1  = (const float*)d_in[20];
    const float* head_W2  = (const float*)d_in[21];

    const int N = in_sizes[0];
    const int E = in_sizes[3];

    char* p = (char*)d_ws;
    size_t off = 0;
    auto carve = [&](size_t bytes) -> void* {
        void* q = p + off;
        off = (off + bytes + 255) & ~(size_t)255;
        return q;
    };
    float*  d_d      = (float*)carve((size_t)E * 4);
    float4* edata    = (float4*)carve((size_t)E * 16);
    int*    sIarr    = (int*)carve((size_t)E * 4);
    int*    hist     = (int*)carve((size_t)N * 4);
    int*    cursor   = (int*)carve((size_t)N * 4);
    int*    partial  = (int*)carve((size_t)SCB * 4);
    float*  x_buf    = (float*)carve((size_t)N * NB * 4);
    short*  xf_buf   = (short*)carve((size_t)N * NB * 2);
    short*  agg      = (short*)carve((size_t)N * NB * 2);
    short*  in2f_WT  = (short*)carve((size_t)6 * NB * NB * 2);
    short*  fW1T     = (short*)carve((size_t)6 * NR * NB * 2);
    short*  fW2T     = (short*)carve((size_t)6 * NB * NB * 2);
    short*  oW1T     = (short*)carve((size_t)6 * NB * NB * 2);
    short*  oW2T     = (short*)carve((size_t)6 * NB * NB * 2);
    short*  hW1T     = (short*)carve((size_t)NB * NB * 2);
    (void)ws_size;

    // weight prep (bf16 transposed)
    {
        int tot = 6 * NB * NB;
        transpose_cvt<<<(tot + 255) / 256, 256, 0, stream>>>(in2f_W, in2f_WT, NB, NB, tot);
        transpose_cvt<<<(tot + 255) / 256, 256, 0, stream>>>(filt_W2, fW2T, NB, NB, tot);
        transpose_cvt<<<(tot + 255) / 256, 256, 0, stream>>>(f2out_W1, oW1T, NB, NB, tot);
        transpose_cvt<<<(tot + 255) / 256, 256, 0, stream>>>(f2out_W2, oW2T, NB, NB, tot);
        int tot1 = 6 * NR * NB;
        transpose_cvt<<<(tot1 + 255) / 256, 256, 0, stream>>>(filt_W1, fW1T, NR, NB, tot1);
        int tot2 = NB * NB;
        transpose_cvt<<<(tot2 + 255) / 256, 256, 0, stream>>>(head_W1, hW1T, NB, NB, tot2);
    }

    // edge prep + idx_i-grouped sort with packed records
    hipMemsetAsync(hist, 0, (size_t)N * 4, stream);
    int nblk_e4 = (E + 1023) / 1024;
    edge_prep4<<<nblk_e4, 256, 0, stream>>>(pos, idx_i, idx_j, d_d, hist, E);
    // multi-block exclusive scan: hist -> cursor (r22)
    scan_reduce<<<SCB, 256, 0, stream>>>(hist, partial, N);
    scan_partials<<<1, SCB, 0, stream>>>(partial);
    scan_expand<<<SCB, 256, 0, stream>>>(hist, partial, cursor, N);
    scatter_sorted4<<<nblk_e4, 256, 0, stream>>>(d_d, idx_i, idx_j, edge_attr,
                                                 cursor, edata, sIarr, E);
    // cursor[a] is now the END of atom a's sorted range; cursor[N-1] = count.

    atom_embed<<<(N * NB + 255) / 256, 256, 0, stream>>>(z, z_res, ele_emb, res_emb, x_buf, N);

    int nblk_atom64 = (N + 63) / 64;
    int nblk_edge = (E + 127) / 128;

    node_in2f_mfma<<<nblk_atom64, 256, 0, stream>>>(x_buf, in2f_WT, xf_buf, N);
    hipMemsetAsync(d_out, 0, (size_t)out_size * sizeof(float), stream);
    hipMemsetAsync(agg, 0, (size_t)N * NB * 2, stream);   // once; node_fused re-zeroes
    for (int i = 0; i < 6; i++) {
        edge_fused_mfma<<<nblk_edge, 256, 0, stream>>>(
            edata, sIarr, cursor, N, edge_emb,
            fW1T + (size_t)i * NR * NB, filt_b1 + (size_t)i * NB,
            fW2T + (size_t)i * NB * NB, filt_b2 + (size_t)i * NB,
            xf_buf, agg);
        if (i < 5) {
            node_fused_mfma<<<nblk_atom64, 128, 0, stream>>>(
                agg, oW1T + (size_t)i * NB * NB, f2out_b1 + (size_t)i * NB,
                oW2T + (size_t)i * NB * NB, f2out_b2 + (size_t)i * NB,
                in2f_WT + (size_t)(i + 1) * NB * NB,
                x_buf, xf_buf, N);
        } else {
            node_out_head_mfma<<<nblk_atom64, 256, 0, stream>>>(
                agg, oW1T + (size_t)i * NB * NB, f2out_b1 + (size_t)i * NB,
                oW2T + (size_t)i * NB * NB, f2out_b2 + (size_t)i * NB,
                x_buf, batch, hW1T, head_b1, head_W2,
                (float*)d_out, N);
        }
    }
}